// Round 1
// baseline (1867.393 us; speedup 1.0000x reference)
//
#include <hip/hip_runtime.h>
#include <math.h>

#define H_HEADS 8
#define C_HID 32
#define D2 256
#define NEG_SLOPE 0.2f

// ---------------- CSR build ----------------

__global__ void zero_kernel(int* counts, int* fill, float* embk, int N) {
    int tid = blockIdx.x * blockDim.x + threadIdx.x;
    if (tid < N + 1) counts[tid] = 0;
    if (tid < N) fill[tid] = 0;
    if (tid < 256) embk[tid] = 0.f;
}

__global__ void count_kernel(const int* __restrict__ ei, int E, int N, int* __restrict__ counts) {
    int tid = blockIdx.x * blockDim.x + threadIdx.x;
    int E2 = E + N;
    if (tid >= E2) return;
    int d = (tid < E) ? ei[E + tid] : (tid - E);
    atomicAdd(&counts[d], 1);
}

__global__ __launch_bounds__(1024) void scan_kernel(const int* __restrict__ counts, int* __restrict__ row_ptr, int N) {
    __shared__ int part[1024];
    int t = threadIdx.x;
    int ipt = (N + 1023) >> 10;
    int begin = t * ipt;
    int end = begin + ipt; if (end > N) end = N;
    int s = 0;
    for (int i = begin; i < end; ++i) s += counts[i];
    part[t] = s;
    __syncthreads();
    for (int d = 1; d < 1024; d <<= 1) {
        int v = 0;
        if (t >= d) v = part[t - d];
        __syncthreads();
        if (t >= d) part[t] += v;
        __syncthreads();
    }
    int run = (t == 0) ? 0 : part[t - 1];
    for (int i = begin; i < end; ++i) { row_ptr[i] = run; run += counts[i]; }
    if (t == 1023) row_ptr[N] = part[1023];
}

__global__ void scatter_kernel(const int* __restrict__ ei, int E, int N,
                               const int* __restrict__ row_ptr, int* __restrict__ fill,
                               int* __restrict__ ein) {
    int tid = blockIdx.x * blockDim.x + threadIdx.x;
    int E2 = E + N;
    if (tid >= E2) return;
    int s, d;
    if (tid < E) { s = ei[tid]; d = ei[E + tid]; } else { s = tid - E; d = s; }
    int pos = row_ptr[d] + atomicAdd(&fill[d], 1);
    ein[pos] = s;
}

// ---------------- GAT pieces ----------------

// h[n,j] = sum_d x[n,d] * W[d,j]   (layer 1: D1 tiny, usually 1)
__global__ void h1_kernel(const float* __restrict__ x, const float* __restrict__ W,
                          float* __restrict__ h, int N, int D1) {
    int tid = blockIdx.x * blockDim.x + threadIdx.x;
    if (tid >= N * 256) return;
    int n = tid >> 8, j = tid & 255;
    float acc = 0.f;
    for (int d = 0; d < D1; ++d) acc += x[n * D1 + d] * W[d * 256 + j];
    h[tid] = acc;
}

// s_src[n,h] = sum_c h[n,h,c]*a_src[h,c]; same for s_dst
__global__ void s_kernel(const float* __restrict__ h, const float* __restrict__ a_src,
                         const float* __restrict__ a_dst, float* __restrict__ s_src,
                         float* __restrict__ s_dst, int N) {
    int tid = blockIdx.x * blockDim.x + threadIdx.x;
    if (tid >= N * 8) return;
    int n = tid >> 3, hh = tid & 7;
    const float* hp = h + n * 256 + hh * 32;
    const float* as = a_src + hh * 32;
    const float* ad = a_dst + hh * 32;
    float ss = 0.f, sd = 0.f;
#pragma unroll
    for (int c = 0; c < 32; ++c) { float v = hp[c]; ss += v * as[c]; sd += v * ad[c]; }
    s_src[tid] = ss;
    s_dst[tid] = sd;
}

__device__ __forceinline__ float lrelu(float x) { return x < 0.f ? NEG_SLOPE * x : x; }

// One wave per dst node: segment softmax over incoming edges + weighted gather.
// out[n,:] = relu( sum_e alpha[e,h] * h[src(e),:] + bias )
__global__ __launch_bounds__(64) void agg_kernel(const float* __restrict__ h,
                                                 const float* __restrict__ s_src,
                                                 const float* __restrict__ s_dst,
                                                 const int* __restrict__ row_ptr,
                                                 const int* __restrict__ ein,
                                                 const float* __restrict__ bias,
                                                 float* __restrict__ out, int N) {
    int n = blockIdx.x;
    int lane = threadIdx.x;
    int e0 = row_ptr[n], e1 = row_ptr[n + 1];
    int h8 = lane & 7;
    float sdn = s_dst[n * 8 + h8];

    // pass 1: per-head max (8 edges x 8 heads per iter)
    float mx = -INFINITY;
    for (int i = e0 + (lane >> 3); i < e1; i += 8) {
        int s = ein[i];
        float e = lrelu(s_src[s * 8 + h8] + sdn);
        mx = fmaxf(mx, e);
    }
    mx = fmaxf(mx, __shfl_xor(mx, 8));
    mx = fmaxf(mx, __shfl_xor(mx, 16));
    mx = fmaxf(mx, __shfl_xor(mx, 32));

    // pass 2: per-head sum of exp
    float den = 0.f;
    for (int i = e0 + (lane >> 3); i < e1; i += 8) {
        int s = ein[i];
        float e = lrelu(s_src[s * 8 + h8] + sdn);
        den += expf(e - mx);
    }
    den += __shfl_xor(den, 8);
    den += __shfl_xor(den, 16);
    den += __shfl_xor(den, 32);

    __shared__ float smx[8], sden[8];
    if (lane < 8) { smx[lane] = mx; sden[lane] = den; }
    __syncthreads();

    // pass 3: weighted gather. lane covers channels 4*lane..4*lane+3 (head = lane>>3)
    int hd = lane >> 3;
    float m3 = smx[hd];
    float d3 = sden[hd] + 1e-16f;
    float sdn3 = s_dst[n * 8 + hd];
    float4 acc = make_float4(0.f, 0.f, 0.f, 0.f);
    for (int i = e0; i < e1; ++i) {
        int s = ein[i];
        float e = lrelu(s_src[s * 8 + hd] + sdn3);
        float alpha = expf(e - m3) / d3;
        const float4 hv = *(const float4*)(h + (size_t)s * 256 + lane * 4);
        acc.x += alpha * hv.x;
        acc.y += alpha * hv.y;
        acc.z += alpha * hv.z;
        acc.w += alpha * hv.w;
    }
    const float4 bv = *(const float4*)(bias + lane * 4);
    float4 o;
    o.x = fmaxf(acc.x + bv.x, 0.f);
    o.y = fmaxf(acc.y + bv.y, 0.f);
    o.z = fmaxf(acc.z + bv.z, 0.f);
    o.w = fmaxf(acc.w + bv.w, 0.f);
    *(float4*)(out + (size_t)n * 256 + lane * 4) = o;
}

// ---------------- fp32 GEMM: C[M,256] = A[M,256] * B[256,256] ----------------

__global__ __launch_bounds__(256) void gemm_kernel(const float* __restrict__ A,
                                                   const float* __restrict__ B,
                                                   float* __restrict__ C, int M) {
    __shared__ float As[64][16];
    __shared__ float Bs[16][64];
    int tid = threadIdx.x;
    int bm = blockIdx.x, bn = blockIdx.y;
    int ty = tid >> 4, tx = tid & 15;
    int r0 = ty * 4, c0 = tx * 4;
    float acc[4][4] = {};
    int arow = tid >> 2;
    int akk = (tid & 3) * 4;
    int brow = tid >> 4;
    int bcol = (tid & 15) * 4;
    int gm_a = bm * 64 + arow;

    for (int kt = 0; kt < 256; kt += 16) {
        float4 av = (gm_a < M) ? *(const float4*)(A + (size_t)gm_a * 256 + kt + akk)
                               : make_float4(0.f, 0.f, 0.f, 0.f);
        *(float4*)&As[arow][akk] = av;
        float4 bv = *(const float4*)(B + (size_t)(kt + brow) * 256 + bn * 64 + bcol);
        *(float4*)&Bs[brow][bcol] = bv;
        __syncthreads();
#pragma unroll
        for (int kk = 0; kk < 16; ++kk) {
            float a0 = As[r0][kk], a1 = As[r0 + 1][kk], a2 = As[r0 + 2][kk], a3 = As[r0 + 3][kk];
            float b0 = Bs[kk][c0], b1 = Bs[kk][c0 + 1], b2 = Bs[kk][c0 + 2], b3 = Bs[kk][c0 + 3];
            acc[0][0] += a0 * b0; acc[0][1] += a0 * b1; acc[0][2] += a0 * b2; acc[0][3] += a0 * b3;
            acc[1][0] += a1 * b0; acc[1][1] += a1 * b1; acc[1][2] += a1 * b2; acc[1][3] += a1 * b3;
            acc[2][0] += a2 * b0; acc[2][1] += a2 * b1; acc[2][2] += a2 * b2; acc[2][3] += a2 * b3;
            acc[3][0] += a3 * b0; acc[3][1] += a3 * b1; acc[3][2] += a3 * b2; acc[3][3] += a3 * b3;
        }
        __syncthreads();
    }
#pragma unroll
    for (int i = 0; i < 4; ++i) {
        int gm = bm * 64 + r0 + i;
        if (gm < M)
            *(float4*)(C + (size_t)gm * 256 + bn * 64 + c0) =
                make_float4(acc[i][0], acc[i][1], acc[i][2], acc[i][3]);
    }
}

// ---------------- mean pool (raw sums; divided in LSTM) ----------------

__global__ __launch_bounds__(256) void pool_kernel(const float* __restrict__ h,
                                                   float* __restrict__ embk, int N) {
    int j = threadIdx.x;
    int n0 = blockIdx.x * 64;
    int n1 = n0 + 64; if (n1 > N) n1 = N;
    float s = 0.f;
    for (int n = n0; n < n1; ++n) s += h[(size_t)n * 256 + j];
    atomicAdd(&embk[j], s);
}

// ---------------- bidirectional LSTM ----------------

__device__ __forceinline__ float sigmoidf(float x) { return 1.f / (1.f + expf(-x)); }

__global__ __launch_bounds__(1024) void lstm_kernel(const float* __restrict__ emb, float invN,
                                                    const float* __restrict__ Wih_f,
                                                    const float* __restrict__ Whh_f,
                                                    const float* __restrict__ bih_f,
                                                    const float* __restrict__ bhh_f,
                                                    const float* __restrict__ Wih_b,
                                                    const float* __restrict__ Whh_b,
                                                    const float* __restrict__ bih_b,
                                                    const float* __restrict__ bhh_b,
                                                    float* __restrict__ out, int K) {
    int dir = blockIdx.x;
    const float* Wih = dir ? Wih_b : Wih_f;
    const float* Whh = dir ? Whh_b : Whh_f;
    const float* bih = dir ? bih_b : bih_f;
    const float* bhh = dir ? bhh_b : bhh_f;

    __shared__ float x[256], hb[256], cb[256], g[1024];
    int t = threadIdx.x;
    if (t < 256) { hb[t] = 0.f; cb[t] = 0.f; }
    __syncthreads();
    float bsum = bih[t] + bhh[t];
    const float* wi = Wih + (size_t)t * 256;
    const float* wh = Whh + (size_t)t * 256;

    for (int step = 0; step < K; ++step) {
        int tt = dir ? (K - 1 - step) : step;
        if (t < 256) x[t] = emb[tt * 256 + t] * invN;
        __syncthreads();
        float acc = bsum;
#pragma unroll 4
        for (int k = 0; k < 256; k += 4) {
            acc += wi[k] * x[k] + wi[k + 1] * x[k + 1] + wi[k + 2] * x[k + 2] + wi[k + 3] * x[k + 3];
        }
#pragma unroll 4
        for (int k = 0; k < 256; k += 4) {
            acc += wh[k] * hb[k] + wh[k + 1] * hb[k + 1] + wh[k + 2] * hb[k + 2] + wh[k + 3] * hb[k + 3];
        }
        g[t] = acc;
        __syncthreads();
        if (t < 256) {
            float ig = sigmoidf(g[t]);
            float fg = sigmoidf(g[256 + t]);
            float gg = tanhf(g[512 + t]);
            float og = sigmoidf(g[768 + t]);
            float cn = fg * cb[t] + ig * gg;
            cb[t] = cn;
            hb[t] = og * tanhf(cn);
        }
        __syncthreads();
    }
    if (t < 256) out[dir * 256 + t] = hb[t];
}

// ---------------- launch ----------------

extern "C" void kernel_launch(void* const* d_in, const int* in_sizes, int n_in,
                              void* d_out, int out_size, void* d_ws, size_t ws_size,
                              hipStream_t stream) {
    const float* xs = (const float*)d_in[0];
    const int* edge_index = (const int*)d_in[1];
    const float* W1 = (const float*)d_in[2];
    const float* a_src1 = (const float*)d_in[3];
    const float* a_dst1 = (const float*)d_in[4];
    const float* b1 = (const float*)d_in[5];
    const float* W2 = (const float*)d_in[6];
    const float* a_src2 = (const float*)d_in[7];
    const float* a_dst2 = (const float*)d_in[8];
    const float* b2 = (const float*)d_in[9];
    const float* Wih_f = (const float*)d_in[10];
    const float* Whh_f = (const float*)d_in[11];
    const float* bih_f = (const float*)d_in[12];
    const float* bhh_f = (const float*)d_in[13];
    const float* Wih_b = (const float*)d_in[14];
    const float* Whh_b = (const float*)d_in[15];
    const float* bih_b = (const float*)d_in[16];
    const float* bhh_b = (const float*)d_in[17];

    const int K = 8;
    int D1 = in_sizes[2] / D2;          // W1 is (D1, 256)
    int N = in_sizes[0] / (K * D1);     // xs is (K, N, D1)
    int E = in_sizes[1] / (2 * K);      // edge_index is (K, 2, E)
    int E2 = E + N;

    // workspace carve (256B aligned)
    char* w = (char*)d_ws;
    auto alloc = [&](size_t bytes) {
        char* p = w;
        w += (bytes + 255) & ~(size_t)255;
        return p;
    };
    int* counts = (int*)alloc((size_t)(N + 1) * 4);
    int* row_ptr = (int*)alloc((size_t)(N + 1) * 4);
    int* fill = (int*)alloc((size_t)N * 4);
    int* ein = (int*)alloc((size_t)E2 * 4);
    float* s_src = (float*)alloc((size_t)N * 8 * 4);
    float* s_dst = (float*)alloc((size_t)N * 8 * 4);
    float* bufA = (float*)alloc((size_t)N * 256 * 4);
    float* bufB = (float*)alloc((size_t)N * 256 * 4);
    float* emb = (float*)alloc((size_t)K * 256 * 4);

    for (int k = 0; k < K; ++k) {
        const int* ei = edge_index + (size_t)k * 2 * E;
        const float* xk = xs + (size_t)k * N * D1;

        zero_kernel<<<(N + 256) / 256, 256, 0, stream>>>(counts, fill, emb + k * 256, N);
        count_kernel<<<(E2 + 255) / 256, 256, 0, stream>>>(ei, E, N, counts);
        scan_kernel<<<1, 1024, 0, stream>>>(counts, row_ptr, N);
        scatter_kernel<<<(E2 + 255) / 256, 256, 0, stream>>>(ei, E, N, row_ptr, fill, ein);

        // layer 1
        h1_kernel<<<(N * 256 + 255) / 256, 256, 0, stream>>>(xk, W1, bufA, N, D1);
        s_kernel<<<(N * 8 + 255) / 256, 256, 0, stream>>>(bufA, a_src1, a_dst1, s_src, s_dst, N);
        agg_kernel<<<N, 64, 0, stream>>>(bufA, s_src, s_dst, row_ptr, ein, b1, bufB, N);

        // layer 2
        gemm_kernel<<<dim3((N + 63) / 64, 4), 256, 0, stream>>>(bufB, W2, bufA, N);
        s_kernel<<<(N * 8 + 255) / 256, 256, 0, stream>>>(bufA, a_src2, a_dst2, s_src, s_dst, N);
        agg_kernel<<<N, 64, 0, stream>>>(bufA, s_src, s_dst, row_ptr, ein, b2, bufB, N);

        // mean pool (raw sum; scaled by 1/N in LSTM)
        pool_kernel<<<(N + 63) / 64, 256, 0, stream>>>(bufB, emb + k * 256, N);
    }

    lstm_kernel<<<2, 1024, 0, stream>>>(emb, 1.f / (float)N,
                                        Wih_f, Whh_f, bih_f, bhh_f,
                                        Wih_b, Whh_b, bih_b, bhh_b,
                                        (float*)d_out, K);
}

// Round 2
// 1461.824 us; speedup vs baseline: 1.2774x; 1.2774x over previous
//
#include <hip/hip_runtime.h>
#include <math.h>

#define H_HEADS 8
#define C_HID 32
#define D2 256
#define NEG_SLOPE 0.2f
#define KSTEPS 8

// ---------------- CSR build ----------------

__global__ void zero_kernel(int* counts, int* fill, float* embk, int N) {
    int tid = blockIdx.x * blockDim.x + threadIdx.x;
    if (tid < N + 1) counts[tid] = 0;
    if (tid < N) fill[tid] = 0;
    if (tid < 256) embk[tid] = 0.f;
}

__global__ void count_kernel(const int* __restrict__ ei, int E, int N, int* __restrict__ counts) {
    int tid = blockIdx.x * blockDim.x + threadIdx.x;
    int E2 = E + N;
    if (tid >= E2) return;
    int d = (tid < E) ? ei[E + tid] : (tid - E);
    atomicAdd(&counts[d], 1);
}

__global__ __launch_bounds__(1024) void scan_kernel(const int* __restrict__ counts, int* __restrict__ row_ptr, int N) {
    __shared__ int part[1024];
    int t = threadIdx.x;
    int ipt = (N + 1023) >> 10;
    int begin = t * ipt;
    int end = begin + ipt; if (end > N) end = N;
    int s = 0;
    for (int i = begin; i < end; ++i) s += counts[i];
    part[t] = s;
    __syncthreads();
    for (int d = 1; d < 1024; d <<= 1) {
        int v = 0;
        if (t >= d) v = part[t - d];
        __syncthreads();
        if (t >= d) part[t] += v;
        __syncthreads();
    }
    int run = (t == 0) ? 0 : part[t - 1];
    for (int i = begin; i < end; ++i) { row_ptr[i] = run; run += counts[i]; }
    if (t == 1023) row_ptr[N] = part[1023];
}

__global__ void scatter_kernel(const int* __restrict__ ei, int E, int N,
                               const int* __restrict__ row_ptr, int* __restrict__ fill,
                               int* __restrict__ ein) {
    int tid = blockIdx.x * blockDim.x + threadIdx.x;
    int E2 = E + N;
    if (tid >= E2) return;
    int s, d;
    if (tid < E) { s = ei[tid]; d = ei[E + tid]; } else { s = tid - E; d = s; }
    int pos = row_ptr[d] + atomicAdd(&fill[d], 1);
    ein[pos] = s;
}

// ---------------- GAT pieces ----------------

__global__ void h1_kernel(const float* __restrict__ x, const float* __restrict__ W,
                          float* __restrict__ h, int N, int D1) {
    int tid = blockIdx.x * blockDim.x + threadIdx.x;
    if (tid >= N * 256) return;
    int n = tid >> 8, j = tid & 255;
    float acc = 0.f;
    for (int d = 0; d < D1; ++d) acc += x[n * D1 + d] * W[d * 256 + j];
    h[tid] = acc;
}

__global__ void s_kernel(const float* __restrict__ h, const float* __restrict__ a_src,
                         const float* __restrict__ a_dst, float* __restrict__ s_src,
                         float* __restrict__ s_dst, int N) {
    int tid = blockIdx.x * blockDim.x + threadIdx.x;
    if (tid >= N * 8) return;
    int n = tid >> 3, hh = tid & 7;
    const float* hp = h + n * 256 + hh * 32;
    const float* as = a_src + hh * 32;
    const float* ad = a_dst + hh * 32;
    float ss = 0.f, sd = 0.f;
#pragma unroll
    for (int c = 0; c < 32; ++c) { float v = hp[c]; ss += v * as[c]; sd += v * ad[c]; }
    s_src[tid] = ss;
    s_dst[tid] = sd;
}

__device__ __forceinline__ float lrelu(float x) { return x < 0.f ? NEG_SLOPE * x : x; }

__global__ __launch_bounds__(64) void agg_kernel(const float* __restrict__ h,
                                                 const float* __restrict__ s_src,
                                                 const float* __restrict__ s_dst,
                                                 const int* __restrict__ row_ptr,
                                                 const int* __restrict__ ein,
                                                 const float* __restrict__ bias,
                                                 float* __restrict__ out, int N) {
    int n = blockIdx.x;
    int lane = threadIdx.x;
    int e0 = row_ptr[n], e1 = row_ptr[n + 1];
    int h8 = lane & 7;
    float sdn = s_dst[n * 8 + h8];

    float mx = -INFINITY;
    for (int i = e0 + (lane >> 3); i < e1; i += 8) {
        int s = ein[i];
        float e = lrelu(s_src[s * 8 + h8] + sdn);
        mx = fmaxf(mx, e);
    }
    mx = fmaxf(mx, __shfl_xor(mx, 8));
    mx = fmaxf(mx, __shfl_xor(mx, 16));
    mx = fmaxf(mx, __shfl_xor(mx, 32));

    float den = 0.f;
    for (int i = e0 + (lane >> 3); i < e1; i += 8) {
        int s = ein[i];
        float e = lrelu(s_src[s * 8 + h8] + sdn);
        den += expf(e - mx);
    }
    den += __shfl_xor(den, 8);
    den += __shfl_xor(den, 16);
    den += __shfl_xor(den, 32);

    __shared__ float smx[8], sden[8];
    if (lane < 8) { smx[lane] = mx; sden[lane] = den; }
    __syncthreads();

    int hd = lane >> 3;
    float m3 = smx[hd];
    float d3 = sden[hd] + 1e-16f;
    float sdn3 = s_dst[n * 8 + hd];
    float4 acc = make_float4(0.f, 0.f, 0.f, 0.f);
    for (int i = e0; i < e1; ++i) {
        int s = ein[i];
        float e = lrelu(s_src[s * 8 + hd] + sdn3);
        float alpha = expf(e - m3) / d3;
        const float4 hv = *(const float4*)(h + (size_t)s * 256 + lane * 4);
        acc.x += alpha * hv.x;
        acc.y += alpha * hv.y;
        acc.z += alpha * hv.z;
        acc.w += alpha * hv.w;
    }
    const float4 bv = *(const float4*)(bias + lane * 4);
    float4 o;
    o.x = fmaxf(acc.x + bv.x, 0.f);
    o.y = fmaxf(acc.y + bv.y, 0.f);
    o.z = fmaxf(acc.z + bv.z, 0.f);
    o.w = fmaxf(acc.w + bv.w, 0.f);
    *(float4*)(out + (size_t)n * 256 + lane * 4) = o;
}

// ---------------- fp32 GEMM: C[M,256] = A[M,256] * B[256,256] ----------------

__global__ __launch_bounds__(256) void gemm_kernel(const float* __restrict__ A,
                                                   const float* __restrict__ B,
                                                   float* __restrict__ C, int M) {
    __shared__ float As[64][16];
    __shared__ float Bs[16][64];
    int tid = threadIdx.x;
    int bm = blockIdx.x, bn = blockIdx.y;
    int ty = tid >> 4, tx = tid & 15;
    int r0 = ty * 4, c0 = tx * 4;
    float acc[4][4] = {};
    int arow = tid >> 2;
    int akk = (tid & 3) * 4;
    int brow = tid >> 4;
    int bcol = (tid & 15) * 4;
    int gm_a = bm * 64 + arow;

    for (int kt = 0; kt < 256; kt += 16) {
        float4 av = (gm_a < M) ? *(const float4*)(A + (size_t)gm_a * 256 + kt + akk)
                               : make_float4(0.f, 0.f, 0.f, 0.f);
        *(float4*)&As[arow][akk] = av;
        float4 bv = *(const float4*)(B + (size_t)(kt + brow) * 256 + bn * 64 + bcol);
        *(float4*)&Bs[brow][bcol] = bv;
        __syncthreads();
#pragma unroll
        for (int kk = 0; kk < 16; ++kk) {
            float a0 = As[r0][kk], a1 = As[r0 + 1][kk], a2 = As[r0 + 2][kk], a3 = As[r0 + 3][kk];
            float b0 = Bs[kk][c0], b1 = Bs[kk][c0 + 1], b2 = Bs[kk][c0 + 2], b3 = Bs[kk][c0 + 3];
            acc[0][0] += a0 * b0; acc[0][1] += a0 * b1; acc[0][2] += a0 * b2; acc[0][3] += a0 * b3;
            acc[1][0] += a1 * b0; acc[1][1] += a1 * b1; acc[1][2] += a1 * b2; acc[1][3] += a1 * b3;
            acc[2][0] += a2 * b0; acc[2][1] += a2 * b1; acc[2][2] += a2 * b2; acc[2][3] += a2 * b3;
            acc[3][0] += a3 * b0; acc[3][1] += a3 * b1; acc[3][2] += a3 * b2; acc[3][3] += a3 * b3;
        }
        __syncthreads();
    }
#pragma unroll
    for (int i = 0; i < 4; ++i) {
        int gm = bm * 64 + r0 + i;
        if (gm < M)
            *(float4*)(C + (size_t)gm * 256 + bn * 64 + c0) =
                make_float4(acc[i][0], acc[i][1], acc[i][2], acc[i][3]);
    }
}

// ---------------- mean pool (raw sums; divided in LSTM) ----------------

__global__ __launch_bounds__(256) void pool_kernel(const float* __restrict__ h,
                                                   float* __restrict__ embk, int N) {
    int j = threadIdx.x;
    int n0 = blockIdx.x * 64;
    int n1 = n0 + 64; if (n1 > N) n1 = N;
    float s = 0.f;
    for (int n = n0; n < n1; ++n) s += h[(size_t)n * 256 + j];
    atomicAdd(&embk[j], s);
}

// ---------------- bidirectional LSTM: 16 blocks/dir, LDS-staged weights ----------------

__device__ __forceinline__ float sigmoidf(float x) { return 1.f / (1.f + expf(-x)); }

__global__ void lstm_init_kernel(int* flags) {
    if (threadIdx.x < 2 * (KSTEPS + 1)) flags[threadIdx.x] = 0;
}

// grid: 32 blocks (dir = bid>>4, seg = bid&15), 256 threads.
// Block owns hidden rows [seg*16, seg*16+16); stages the 64 corresponding
// gate rows of Whh and Wih in LDS. gx (input proj + biases) precomputed for
// all steps. Recurrence synced across the 16 peer blocks via device-scope flags.
__global__ __launch_bounds__(256) void lstm_rec_kernel(
    const float* __restrict__ emb, float invN,
    const float* __restrict__ Wih_f, const float* __restrict__ Whh_f,
    const float* __restrict__ bih_f, const float* __restrict__ bhh_f,
    const float* __restrict__ Wih_b, const float* __restrict__ Whh_b,
    const float* __restrict__ bih_b, const float* __restrict__ bhh_b,
    float* __restrict__ hbuf,   // [2][K+1][256]
    int* __restrict__ flags,    // [2][K+1] (pre-zeroed)
    float* __restrict__ out) {
    int dir = blockIdx.x >> 4;
    int seg = blockIdx.x & 15;
    const float* Wih = dir ? Wih_b : Wih_f;
    const float* Whh = dir ? Whh_b : Whh_f;
    const float* bih = dir ? bih_b : bih_f;
    const float* bhh = dir ? bhh_b : bhh_f;

    __shared__ float wh[64 * 256];        // 64 KB
    __shared__ float wi[64 * 256];        // 64 KB
    __shared__ float xs_s[KSTEPS * 256];  // 8 KB
    __shared__ float gx[KSTEPS][64];      // 2 KB
    __shared__ float garr[64];
    __shared__ float hprev_s[256];

    int tid = threadIdx.x;

    // stage weights (coalesced along columns). lrow = gate*16 + tl -> global row gate*256 + seg*16 + tl
    for (int idx = tid; idx < 64 * 256; idx += 256) {
        int lrow = idx >> 8, col = idx & 255;
        int grow = ((lrow >> 4) << 8) + seg * 16 + (lrow & 15);
        wh[idx] = Whh[(size_t)grow * 256 + col];
        wi[idx] = Wih[(size_t)grow * 256 + col];
    }
    for (int idx = tid; idx < KSTEPS * 256; idx += 256) xs_s[idx] = emb[idx] * invN;
    __syncthreads();

    // gx[step][lrow] = bias + dot(wi[lrow], x[step]); rotate k to avoid bank conflicts
    for (int d = tid; d < KSTEPS * 64; d += 256) {
        int st = d >> 6, lr = d & 63;
        const float* wr = &wi[lr << 8];
        const float* xr = &xs_s[st << 8];
        int r = (tid & 63) << 2;
        float acc = 0.f;
#pragma unroll 8
        for (int kk = 0; kk < 256; kk += 4) {
            int k2 = (kk + r) & 255;
            acc += wr[k2] * xr[k2] + wr[k2 + 1] * xr[k2 + 1] +
                   wr[k2 + 2] * xr[k2 + 2] + wr[k2 + 3] * xr[k2 + 3];
        }
        int grow = ((lr >> 4) << 8) + seg * 16 + (lr & 15);
        gx[st][lr] = acc + bih[grow] + bhh[grow];
    }

    int* flag = flags + dir * (KSTEPS + 1);
    float* hb = hbuf + dir * (KSTEPS + 1) * 256;

    // h0 = 0 (each block writes its own 16 entries)
    if (tid < 16)
        __hip_atomic_store(&hb[seg * 16 + tid], 0.f, __ATOMIC_RELAXED, __HIP_MEMORY_SCOPE_AGENT);
    __syncthreads();
    __threadfence();
    if (tid == 0) atomicAdd(&flag[0], 1);

    float c_reg = 0.f;  // carried by threads tid<16

    for (int step = 0; step < KSTEPS; ++step) {
        if (tid == 0) {
            while (__hip_atomic_load(&flag[step], __ATOMIC_ACQUIRE, __HIP_MEMORY_SCOPE_AGENT) < 16) {
                __builtin_amdgcn_s_sleep(1);
            }
        }
        __syncthreads();
        hprev_s[tid] = __hip_atomic_load(&hb[step * 256 + tid], __ATOMIC_RELAXED,
                                         __HIP_MEMORY_SCOPE_AGENT);
        __syncthreads();

        // 64 dots of length 256: 4 threads/dot (p = tid&3 covers 64 elems each)
        int d = tid >> 2, p = tid & 3;
        const float* wr = &wh[(d << 8) + (p << 6)];
        const float* hr = &hprev_s[p << 6];
        int r = tid & 63;
        float acc = 0.f;
#pragma unroll 8
        for (int kk = 0; kk < 64; ++kk) {
            int k2 = (kk + r) & 63;
            acc += wr[k2] * hr[k2];
        }
        acc += __shfl_xor(acc, 1);
        acc += __shfl_xor(acc, 2);
        if (p == 0) garr[d] = acc;
        __syncthreads();

        if (tid < 16) {
            float ig = sigmoidf(garr[tid] + gx[step][tid]);
            float fg = sigmoidf(garr[16 + tid] + gx[step][16 + tid]);
            float gg = tanhf(garr[32 + tid] + gx[step][32 + tid]);
            float og = sigmoidf(garr[48 + tid] + gx[step][48 + tid]);
            float cn = fg * c_reg + ig * gg;
            c_reg = cn;
            float hn = og * tanhf(cn);
            __hip_atomic_store(&hb[(step + 1) * 256 + seg * 16 + tid], hn, __ATOMIC_RELAXED,
                               __HIP_MEMORY_SCOPE_AGENT);
        }
        __threadfence();
        __syncthreads();
        if (tid == 0) atomicAdd(&flag[step + 1], 1);
        __syncthreads();
    }

    if (tid < 16) out[dir * 256 + seg * 16 + tid] = hb[KSTEPS * 256 + seg * 16 + tid];
}

// ---------------- launch ----------------

extern "C" void kernel_launch(void* const* d_in, const int* in_sizes, int n_in,
                              void* d_out, int out_size, void* d_ws, size_t ws_size,
                              hipStream_t stream) {
    const float* xs = (const float*)d_in[0];
    const int* edge_index = (const int*)d_in[1];
    const float* W1 = (const float*)d_in[2];
    const float* a_src1 = (const float*)d_in[3];
    const float* a_dst1 = (const float*)d_in[4];
    const float* b1 = (const float*)d_in[5];
    const float* W2 = (const float*)d_in[6];
    const float* a_src2 = (const float*)d_in[7];
    const float* a_dst2 = (const float*)d_in[8];
    const float* b2 = (const float*)d_in[9];
    const float* Wih_f = (const float*)d_in[10];
    const float* Whh_f = (const float*)d_in[11];
    const float* bih_f = (const float*)d_in[12];
    const float* bhh_f = (const float*)d_in[13];
    const float* Wih_b = (const float*)d_in[14];
    const float* Whh_b = (const float*)d_in[15];
    const float* bih_b = (const float*)d_in[16];
    const float* bhh_b = (const float*)d_in[17];

    const int K = KSTEPS;
    int D1 = in_sizes[2] / D2;
    int N = in_sizes[0] / (K * D1);
    int E = in_sizes[1] / (2 * K);
    int E2 = E + N;

    char* w = (char*)d_ws;
    auto alloc = [&](size_t bytes) {
        char* p = w;
        w += (bytes + 255) & ~(size_t)255;
        return p;
    };
    int* counts = (int*)alloc((size_t)(N + 1) * 4);
    int* row_ptr = (int*)alloc((size_t)(N + 1) * 4);
    int* fill = (int*)alloc((size_t)N * 4);
    int* ein = (int*)alloc((size_t)E2 * 4);
    float* s_src = (float*)alloc((size_t)N * 8 * 4);
    float* s_dst = (float*)alloc((size_t)N * 8 * 4);
    float* bufA = (float*)alloc((size_t)N * 256 * 4);
    float* bufB = (float*)alloc((size_t)N * 256 * 4);
    float* emb = (float*)alloc((size_t)K * 256 * 4);
    float* hbuf = (float*)alloc((size_t)2 * (K + 1) * 256 * 4);
    int* flags = (int*)alloc((size_t)2 * (K + 1) * 4);

    lstm_init_kernel<<<1, 64, 0, stream>>>(flags);

    for (int k = 0; k < K; ++k) {
        const int* ei = edge_index + (size_t)k * 2 * E;
        const float* xk = xs + (size_t)k * N * D1;

        zero_kernel<<<(N + 256) / 256, 256, 0, stream>>>(counts, fill, emb + k * 256, N);
        count_kernel<<<(E2 + 255) / 256, 256, 0, stream>>>(ei, E, N, counts);
        scan_kernel<<<1, 1024, 0, stream>>>(counts, row_ptr, N);
        scatter_kernel<<<(E2 + 255) / 256, 256, 0, stream>>>(ei, E, N, row_ptr, fill, ein);

        h1_kernel<<<(N * 256 + 255) / 256, 256, 0, stream>>>(xk, W1, bufA, N, D1);
        s_kernel<<<(N * 8 + 255) / 256, 256, 0, stream>>>(bufA, a_src1, a_dst1, s_src, s_dst, N);
        agg_kernel<<<N, 64, 0, stream>>>(bufA, s_src, s_dst, row_ptr, ein, b1, bufB, N);

        gemm_kernel<<<dim3((N + 63) / 64, 4), 256, 0, stream>>>(bufB, W2, bufA, N);
        s_kernel<<<(N * 8 + 255) / 256, 256, 0, stream>>>(bufA, a_src2, a_dst2, s_src, s_dst, N);
        agg_kernel<<<N, 64, 0, stream>>>(bufA, s_src, s_dst, row_ptr, ein, b2, bufB, N);

        pool_kernel<<<(N + 63) / 64, 256, 0, stream>>>(bufB, emb + k * 256, N);
    }

    lstm_rec_kernel<<<32, 256, 0, stream>>>(emb, 1.f / (float)N,
                                            Wih_f, Whh_f, bih_f, bhh_f,
                                            Wih_b, Whh_b, bih_b, bhh_b,
                                            hbuf, flags, (float*)d_out);
}

// Round 3
// 1239.459 us; speedup vs baseline: 1.5066x; 1.1794x over previous
//
#include <hip/hip_runtime.h>
#include <math.h>

#define H_HEADS 8
#define C_HID 32
#define D2 256
#define NEG_SLOPE 0.2f
#define KSTEPS 8

// ---------------- CSR build ----------------

__global__ void zero_kernel(int* counts, int* fill, float* embk, int N) {
    int tid = blockIdx.x * blockDim.x + threadIdx.x;
    if (tid < N + 1) counts[tid] = 0;
    if (tid < N) fill[tid] = 0;
    if (tid < 256) embk[tid] = 0.f;
}

__global__ void count_kernel(const int* __restrict__ ei, int E, int N, int* __restrict__ counts) {
    int tid = blockIdx.x * blockDim.x + threadIdx.x;
    int E2 = E + N;
    if (tid >= E2) return;
    int d = (tid < E) ? ei[E + tid] : (tid - E);
    atomicAdd(&counts[d], 1);
}

__global__ __launch_bounds__(1024) void scan_kernel(const int* __restrict__ counts, int* __restrict__ row_ptr, int N) {
    __shared__ int part[1024];
    int t = threadIdx.x;
    int ipt = (N + 1023) >> 10;
    int begin = t * ipt;
    int end = begin + ipt; if (end > N) end = N;
    int s = 0;
    for (int i = begin; i < end; ++i) s += counts[i];
    part[t] = s;
    __syncthreads();
    for (int d = 1; d < 1024; d <<= 1) {
        int v = 0;
        if (t >= d) v = part[t - d];
        __syncthreads();
        if (t >= d) part[t] += v;
        __syncthreads();
    }
    int run = (t == 0) ? 0 : part[t - 1];
    for (int i = begin; i < end; ++i) { row_ptr[i] = run; run += counts[i]; }
    if (t == 1023) row_ptr[N] = part[1023];
}

__global__ void scatter_kernel(const int* __restrict__ ei, int E, int N,
                               const int* __restrict__ row_ptr, int* __restrict__ fill,
                               int* __restrict__ ein) {
    int tid = blockIdx.x * blockDim.x + threadIdx.x;
    int E2 = E + N;
    if (tid >= E2) return;
    int s, d;
    if (tid < E) { s = ei[tid]; d = ei[E + tid]; } else { s = tid - E; d = s; }
    int pos = row_ptr[d] + atomicAdd(&fill[d], 1);
    ein[pos] = s;
}

// ---------------- GAT pieces ----------------

__device__ __forceinline__ float lrelu(float x) { return x < 0.f ? NEG_SLOPE * x : x; }

// P[h] = sum_c W1[h*32+c]*a_src[h,c]  (h<8: src, h>=8: dst)  -- valid for D1==1
__global__ void pvec_kernel(const float* __restrict__ W1, const float* __restrict__ a_src,
                            const float* __restrict__ a_dst, float* __restrict__ P) {
    int t = threadIdx.x;
    if (t < 16) {
        int h = t & 7;
        const float* a = (t >= 8) ? a_dst : a_src;
        float s = 0.f;
        for (int c = 0; c < 32; ++c) s += W1[h * 32 + c] * a[h * 32 + c];
        P[t] = s;
    }
}

// generic layer-1 projection (fallback D1 != 1)
__global__ void h1_kernel(const float* __restrict__ x, const float* __restrict__ W,
                          float* __restrict__ h, int N, int D1) {
    int tid = blockIdx.x * blockDim.x + threadIdx.x;
    if (tid >= N * 256) return;
    int n = tid >> 8, j = tid & 255;
    float acc = 0.f;
    for (int d = 0; d < D1; ++d) acc += x[n * D1 + d] * W[d * 256 + j];
    h[tid] = acc;
}

__global__ void s_kernel(const float* __restrict__ h, const float* __restrict__ a_src,
                         const float* __restrict__ a_dst, float* __restrict__ s_src,
                         float* __restrict__ s_dst, int N) {
    int tid = blockIdx.x * blockDim.x + threadIdx.x;
    if (tid >= N * 8) return;
    int n = tid >> 3, hh = tid & 7;
    const float* hp = h + n * 256 + hh * 32;
    const float* as = a_src + hh * 32;
    const float* ad = a_dst + hh * 32;
    float ss = 0.f, sd = 0.f;
#pragma unroll
    for (int c = 0; c < 32; ++c) { float v = hp[c]; ss += v * as[c]; sd += v * ad[c]; }
    s_src[tid] = ss;
    s_dst[tid] = sd;
}

// Layer-1 rank-1 fast path: per dst node, softmax over incoming edges of
// e = lrelu(x[s]*Ps[h] + x[n]*Pd[h]);  S[h] = sum alpha*x[s];
// out[n,h,c] = relu(S[h]*W1[h*32+c] + b1).  4 nodes per 256-thr block, 1 wave/node.
__global__ __launch_bounds__(256) void agg1_kernel(const float* __restrict__ x,
                                                   const float* __restrict__ P,
                                                   const int* __restrict__ row_ptr,
                                                   const int* __restrict__ ein,
                                                   const float* __restrict__ W1,
                                                   const float* __restrict__ b1,
                                                   float* __restrict__ out, int N) {
    int n = blockIdx.x * 4 + (threadIdx.x >> 6);
    if (n >= N) return;
    int lane = threadIdx.x & 63;
    int e0 = row_ptr[n], e1 = row_ptr[n + 1];
    int h8 = lane & 7;
    float Ps = P[h8], Pd = P[8 + h8];
    float base = x[n] * Pd;

    float mx = -INFINITY;
    for (int i = e0 + (lane >> 3); i < e1; i += 8) {
        float xs = x[ein[i]];
        mx = fmaxf(mx, lrelu(xs * Ps + base));
    }
    mx = fmaxf(mx, __shfl_xor(mx, 8));
    mx = fmaxf(mx, __shfl_xor(mx, 16));
    mx = fmaxf(mx, __shfl_xor(mx, 32));

    float num = 0.f, den = 0.f;
    for (int i = e0 + (lane >> 3); i < e1; i += 8) {
        float xs = x[ein[i]];
        float w = expf(lrelu(xs * Ps + base) - mx);
        num += w * xs;
        den += w;
    }
    num += __shfl_xor(num, 8);  den += __shfl_xor(den, 8);
    num += __shfl_xor(num, 16); den += __shfl_xor(den, 16);
    num += __shfl_xor(num, 32); den += __shfl_xor(den, 32);
    float S = num / (den + 1e-16f);

    int hd = lane >> 3;
    float Sh = __shfl(S, hd);
    const float4 wv = *(const float4*)(W1 + lane * 4);
    const float4 bv = *(const float4*)(b1 + lane * 4);
    float4 o;
    o.x = fmaxf(Sh * wv.x + bv.x, 0.f);
    o.y = fmaxf(Sh * wv.y + bv.y, 0.f);
    o.z = fmaxf(Sh * wv.z + bv.z, 0.f);
    o.w = fmaxf(Sh * wv.w + bv.w, 0.f);
    *(float4*)(out + (size_t)n * 256 + lane * 4) = o;
}

// Full-rank aggregation (layer 2 + generic layer 1). 4 nodes/block, 1 wave/node.
// pass1: per-head max; pass2: gather with fused exp-sum; divide once at the end.
__global__ __launch_bounds__(256) void agg2_kernel(const float* __restrict__ h,
                                                   const float* __restrict__ s_src,
                                                   const float* __restrict__ s_dst,
                                                   const int* __restrict__ row_ptr,
                                                   const int* __restrict__ ein,
                                                   const float* __restrict__ bias,
                                                   float* __restrict__ out, int N) {
    int n = blockIdx.x * 4 + (threadIdx.x >> 6);
    if (n >= N) return;
    int lane = threadIdx.x & 63;
    int e0 = row_ptr[n], e1 = row_ptr[n + 1];
    int h8 = lane & 7;
    float sd8 = s_dst[n * 8 + h8];

    float mx = -INFINITY;
    for (int i = e0 + (lane >> 3); i < e1; i += 8) {
        int s = ein[i];
        mx = fmaxf(mx, lrelu(s_src[s * 8 + h8] + sd8));
    }
    mx = fmaxf(mx, __shfl_xor(mx, 8));
    mx = fmaxf(mx, __shfl_xor(mx, 16));
    mx = fmaxf(mx, __shfl_xor(mx, 32));

    int hd = lane >> 3;
    float m = __shfl(mx, hd);
    float sdh = __shfl(sd8, hd);

    float den = 0.f;
    float4 acc = make_float4(0.f, 0.f, 0.f, 0.f);
    int i = e0;
    int sA = ein[i];
    for (; i < e1; ++i) {
        int sN = (i + 1 < e1) ? ein[i + 1] : 0;
        const float4 hv = *(const float4*)(h + (size_t)sA * 256 + lane * 4);
        float w = expf(lrelu(s_src[sA * 8 + hd] + sdh) - m);
        den += w;
        acc.x += w * hv.x;
        acc.y += w * hv.y;
        acc.z += w * hv.z;
        acc.w += w * hv.w;
        sA = sN;
    }
    float dE = den + 1e-16f;
    const float4 bv = *(const float4*)(bias + lane * 4);
    float4 o;
    o.x = fmaxf(acc.x / dE + bv.x, 0.f);
    o.y = fmaxf(acc.y / dE + bv.y, 0.f);
    o.z = fmaxf(acc.z / dE + bv.z, 0.f);
    o.w = fmaxf(acc.w / dE + bv.w, 0.f);
    *(float4*)(out + (size_t)n * 256 + lane * 4) = o;
}

// ---------------- fp32 GEMM: C[M,256] = A[M,256] * B[256,256] ----------------
// 128x64 tile, 256 threads, 8x4 per thread, A transposed in LDS (padded).

__global__ __launch_bounds__(256) void gemm_kernel(const float* __restrict__ A,
                                                   const float* __restrict__ B,
                                                   float* __restrict__ C, int M) {
    __shared__ float Ast[16][132];
    __shared__ float Bs[16][64];
    int tid = threadIdx.x;
    int bm = blockIdx.x, bn = blockIdx.y;
    int ty = tid >> 4, tx = tid & 15;
    int r0 = ty * 8, c0 = tx * 4;
    float acc[8][4] = {};
    int arow = tid >> 2;
    int ak = (tid & 3) * 4;
    int brow = tid >> 4;
    int bcol = (tid & 15) * 4;

    for (int kt = 0; kt < 256; kt += 16) {
#pragma unroll
        for (int half = 0; half < 2; ++half) {
            int r = arow + half * 64;
            int gr = bm * 128 + r;
            float4 av = (gr < M) ? *(const float4*)(A + (size_t)gr * 256 + kt + ak)
                                 : make_float4(0.f, 0.f, 0.f, 0.f);
            Ast[ak + 0][r] = av.x;
            Ast[ak + 1][r] = av.y;
            Ast[ak + 2][r] = av.z;
            Ast[ak + 3][r] = av.w;
        }
        float4 bv = *(const float4*)(B + (size_t)(kt + brow) * 256 + bn * 64 + bcol);
        *(float4*)&Bs[brow][bcol] = bv;
        __syncthreads();
#pragma unroll
        for (int kk = 0; kk < 16; ++kk) {
            float4 a0 = *(const float4*)&Ast[kk][r0];
            float4 a1 = *(const float4*)&Ast[kk][r0 + 4];
            float4 b = *(const float4*)&Bs[kk][c0];
            float ar[8] = {a0.x, a0.y, a0.z, a0.w, a1.x, a1.y, a1.z, a1.w};
            float br[4] = {b.x, b.y, b.z, b.w};
#pragma unroll
            for (int i2 = 0; i2 < 8; ++i2)
#pragma unroll
                for (int j2 = 0; j2 < 4; ++j2) acc[i2][j2] += ar[i2] * br[j2];
        }
        __syncthreads();
    }
#pragma unroll
    for (int i2 = 0; i2 < 8; ++i2) {
        int gm = bm * 128 + r0 + i2;
        if (gm < M)
            *(float4*)(C + (size_t)gm * 256 + bn * 64 + c0) =
                make_float4(acc[i2][0], acc[i2][1], acc[i2][2], acc[i2][3]);
    }
}

// ---------------- mean pool (raw sums; divided in LSTM gx) ----------------

__global__ __launch_bounds__(256) void pool_kernel(const float* __restrict__ h,
                                                   float* __restrict__ embk, int N) {
    int j = threadIdx.x;
    int n0 = blockIdx.x * 64;
    int n1 = n0 + 64; if (n1 > N) n1 = N;
    float s = 0.f;
    for (int n = n0; n < n1; ++n) s += h[(size_t)n * 256 + j];
    atomicAdd(&embk[j], s);
}

// ---------------- bidirectional LSTM ----------------

__global__ void lstm_init_kernel(int* flags) {
    if (threadIdx.x < 2 * (KSTEPS + 1)) flags[threadIdx.x] = 0;
}

// 128 blocks: dir = bid>>6, g = bid&63 -> gate-rows [g*16, g*16+16).
// Computes gx[dir][step][grow] = bias + Wih[grow]·x[step] (f64 acc) and warms Whh.
__global__ __launch_bounds__(256) void lstm_gx_kernel(
    const float* __restrict__ emb, float invN,
    const float* __restrict__ Wih_f, const float* __restrict__ bih_f, const float* __restrict__ bhh_f,
    const float* __restrict__ Wih_b, const float* __restrict__ bih_b, const float* __restrict__ bhh_b,
    const float* __restrict__ Whh_f, const float* __restrict__ Whh_b,
    float* __restrict__ gx, float* __restrict__ dummy) {
    int bid = blockIdx.x;
    int dir = bid >> 6, g = bid & 63;
    const float* Wih = dir ? Wih_b : Wih_f;
    const float* bih = dir ? bih_b : bih_f;
    const float* bhh = dir ? bhh_b : bhh_f;
    const float* Whh = dir ? Whh_b : Whh_f;

    __shared__ float wr_s[16 * 256];      // 16 KB
    __shared__ float xs_s[KSTEPS * 256];  // 8 KB
    int tid = threadIdx.x;

    for (int v = tid; v < 16 * 64; v += 256)
        *(float4*)&wr_s[v * 4] = *(const float4*)(Wih + (size_t)g * 16 * 256 + v * 4);
    for (int idx = tid; idx < KSTEPS * 256; idx += 256) xs_s[idx] = emb[idx] * invN;

    // warm Whh rows (same range) into L2/L3
    float wsum = 0.f;
    for (int v = tid; v < 16 * 64; v += 256) {
        float4 t = *(const float4*)(Whh + (size_t)g * 16 * 256 + v * 4);
        wsum += t.x + t.y + t.z + t.w;
    }
    dummy[bid * 256 + tid] = wsum;
    __syncthreads();

    int d = tid >> 1, p = tid & 1;      // d: (row r, step st); p: 128-halves
    int r = d >> 3, st = d & 7;
    const float* wrow = &wr_s[r * 256 + p * 128];
    const float* xrow = &xs_s[st * 256 + p * 128];
    int rot = tid & 63;
    double acc = 0.0;
    for (int k = 0; k < 128; ++k) {
        int k2 = (k + rot) & 127;
        acc += (double)wrow[k2] * (double)xrow[k2];
    }
    acc += __shfl_xor(acc, 1);
    if (p == 0) {
        int grow = g * 16 + r;
        double v = acc + (double)bih[grow] + (double)bhh[grow];
        gx[(size_t)(dir * KSTEPS + st) * 1024 + grow] = (float)v;
    }
}

// 32 blocks: dir = bid>>4, seg = bid&15. Stages 64 gate-rows of Whh (warm),
// recurrence with f64 dot + f64 gate math, peer-block sync via device flags.
__global__ __launch_bounds__(256) void lstm_rec_kernel(
    const float* __restrict__ Whh_f, const float* __restrict__ Whh_b,
    const float* __restrict__ gx,
    float* __restrict__ hbuf,   // [2][K+1][256]
    int* __restrict__ flags,    // [2][K+1]
    float* __restrict__ out) {
    int dir = blockIdx.x >> 4;
    int seg = blockIdx.x & 15;
    const float* Whh = dir ? Whh_b : Whh_f;

    __shared__ float wh[64 * 256];  // 64 KB
    __shared__ double garr[64];
    __shared__ float hprev_s[256];
    int tid = threadIdx.x;

    for (int v = tid; v < 64 * 64; v += 256) {
        int lrow = v >> 6;
        int c4 = (v & 63) * 4;
        int grow = ((lrow >> 4) << 8) + seg * 16 + (lrow & 15);
        *(float4*)&wh[lrow * 256 + c4] = *(const float4*)(Whh + (size_t)grow * 256 + c4);
    }

    int* flag = flags + dir * (KSTEPS + 1);
    float* hb = hbuf + dir * (KSTEPS + 1) * 256;

    if (tid < 16)
        __hip_atomic_store(&hb[seg * 16 + tid], 0.f, __ATOMIC_RELAXED, __HIP_MEMORY_SCOPE_AGENT);
    __syncthreads();
    __threadfence();
    if (tid == 0) atomicAdd(&flag[0], 1);

    double c_reg = 0.0;

    for (int step = 0; step < KSTEPS; ++step) {
        if (tid == 0) {
            while (__hip_atomic_load(&flag[step], __ATOMIC_ACQUIRE, __HIP_MEMORY_SCOPE_AGENT) < 16) {
                __builtin_amdgcn_s_sleep(1);
            }
        }
        __syncthreads();
        hprev_s[tid] = __hip_atomic_load(&hb[step * 256 + tid], __ATOMIC_RELAXED,
                                         __HIP_MEMORY_SCOPE_AGENT);
        __syncthreads();

        int d = tid >> 2, p = tid & 3;
        const float* wr = &wh[(d << 8) + (p << 6)];
        const float* hr = &hprev_s[p << 6];
        int rot = tid & 63;
        double acc = 0.0;
        for (int k = 0; k < 64; ++k) {
            int k2 = (k + rot) & 63;
            acc += (double)wr[k2] * (double)hr[k2];
        }
        acc += __shfl_xor(acc, 1);
        acc += __shfl_xor(acc, 2);
        if (p == 0) garr[d] = acc;
        __syncthreads();

        if (tid < 16) {
            const float* gxs = gx + (size_t)(dir * KSTEPS + step) * 1024 + seg * 16 + tid;
            double gi = garr[tid] + (double)gxs[0];
            double gf = garr[16 + tid] + (double)gxs[256];
            double gg = garr[32 + tid] + (double)gxs[512];
            double go = garr[48 + tid] + (double)gxs[768];
            double ig = 1.0 / (1.0 + exp(-gi));
            double fg = 1.0 / (1.0 + exp(-gf));
            double gt = tanh(gg);
            double og = 1.0 / (1.0 + exp(-go));
            double cn = fg * c_reg + ig * gt;
            c_reg = cn;
            float hn = (float)(og * tanh(cn));
            __hip_atomic_store(&hb[(step + 1) * 256 + seg * 16 + tid], hn, __ATOMIC_RELAXED,
                               __HIP_MEMORY_SCOPE_AGENT);
        }
        __threadfence();
        __syncthreads();
        if (tid == 0) atomicAdd(&flag[step + 1], 1);
        __syncthreads();
    }

    if (tid < 16) out[dir * 256 + seg * 16 + tid] = hb[KSTEPS * 256 + seg * 16 + tid];
}

// ---------------- launch ----------------

extern "C" void kernel_launch(void* const* d_in, const int* in_sizes, int n_in,
                              void* d_out, int out_size, void* d_ws, size_t ws_size,
                              hipStream_t stream) {
    const float* xs = (const float*)d_in[0];
    const int* edge_index = (const int*)d_in[1];
    const float* W1 = (const float*)d_in[2];
    const float* a_src1 = (const float*)d_in[3];
    const float* a_dst1 = (const float*)d_in[4];
    const float* b1 = (const float*)d_in[5];
    const float* W2 = (const float*)d_in[6];
    const float* a_src2 = (const float*)d_in[7];
    const float* a_dst2 = (const float*)d_in[8];
    const float* b2 = (const float*)d_in[9];
    const float* Wih_f = (const float*)d_in[10];
    const float* Whh_f = (const float*)d_in[11];
    const float* bih_f = (const float*)d_in[12];
    const float* bhh_f = (const float*)d_in[13];
    const float* Wih_b = (const float*)d_in[14];
    const float* Whh_b = (const float*)d_in[15];
    const float* bih_b = (const float*)d_in[16];
    const float* bhh_b = (const float*)d_in[17];

    const int K = KSTEPS;
    int D1 = in_sizes[2] / D2;
    int N = in_sizes[0] / (K * D1);
    int E = in_sizes[1] / (2 * K);
    int E2 = E + N;

    char* w = (char*)d_ws;
    auto alloc = [&](size_t bytes) {
        char* p = w;
        w += (bytes + 255) & ~(size_t)255;
        return p;
    };
    int* counts = (int*)alloc((size_t)(N + 1) * 4);
    int* row_ptr = (int*)alloc((size_t)(N + 1) * 4);
    int* fill = (int*)alloc((size_t)N * 4);
    int* ein = (int*)alloc((size_t)E2 * 4);
    float* s_src = (float*)alloc((size_t)N * 8 * 4);
    float* s_dst = (float*)alloc((size_t)N * 8 * 4);
    float* bufA = (float*)alloc((size_t)N * 256 * 4);
    float* bufB = (float*)alloc((size_t)N * 256 * 4);
    float* emb = (float*)alloc((size_t)K * 256 * 4);
    float* hbuf = (float*)alloc((size_t)2 * (K + 1) * 256 * 4);
    int* flags = (int*)alloc((size_t)2 * (K + 1) * 4);
    float* Pvec = (float*)alloc(16 * 4);
    float* gxbuf = (float*)alloc((size_t)2 * K * 1024 * 4);
    float* dummy = (float*)alloc((size_t)128 * 256 * 4);

    lstm_init_kernel<<<1, 64, 0, stream>>>(flags);
    if (D1 == 1) pvec_kernel<<<1, 64, 0, stream>>>(W1, a_src1, a_dst1, Pvec);

    int nblk4 = (N + 3) / 4;
    for (int k = 0; k < K; ++k) {
        const int* ei = edge_index + (size_t)k * 2 * E;
        const float* xk = xs + (size_t)k * N * D1;

        zero_kernel<<<(N + 256) / 256, 256, 0, stream>>>(counts, fill, emb + k * 256, N);
        count_kernel<<<(E2 + 255) / 256, 256, 0, stream>>>(ei, E, N, counts);
        scan_kernel<<<1, 1024, 0, stream>>>(counts, row_ptr, N);
        scatter_kernel<<<(E2 + 255) / 256, 256, 0, stream>>>(ei, E, N, row_ptr, fill, ein);

        if (D1 == 1) {
            agg1_kernel<<<nblk4, 256, 0, stream>>>(xk, Pvec, row_ptr, ein, W1, b1, bufB, N);
        } else {
            h1_kernel<<<(N * 256 + 255) / 256, 256, 0, stream>>>(xk, W1, bufA, N, D1);
            s_kernel<<<(N * 8 + 255) / 256, 256, 0, stream>>>(bufA, a_src1, a_dst1, s_src, s_dst, N);
            agg2_kernel<<<nblk4, 256, 0, stream>>>(bufA, s_src, s_dst, row_ptr, ein, b1, bufB, N);
        }

        gemm_kernel<<<dim3((N + 127) / 128, 4), 256, 0, stream>>>(bufB, W2, bufA, N);
        s_kernel<<<(N * 8 + 255) / 256, 256, 0, stream>>>(bufA, a_src2, a_dst2, s_src, s_dst, N);
        agg2_kernel<<<nblk4, 256, 0, stream>>>(bufA, s_src, s_dst, row_ptr, ein, b2, bufB, N);

        pool_kernel<<<(N + 63) / 64, 256, 0, stream>>>(bufB, emb + k * 256, N);
    }

    lstm_gx_kernel<<<128, 256, 0, stream>>>(emb, 1.f / (float)N,
                                            Wih_f, bih_f, bhh_f,
                                            Wih_b, bih_b, bhh_b,
                                            Whh_f, Whh_b, gxbuf, dummy);
    lstm_rec_kernel<<<32, 256, 0, stream>>>(Whh_f, Whh_b, gxbuf, hbuf, flags, (float*)d_out);
}

// Round 4
// 679.785 us; speedup vs baseline: 2.7470x; 1.8233x over previous
//
#include <hip/hip_runtime.h>
#include <math.h>

#define H_HEADS 8
#define C_HID 32
#define D2 256
#define NEG_SLOPE 0.2f
#define KSTEPS 8

__device__ __forceinline__ float lrelu(float x) { return x < 0.f ? NEG_SLOPE * x : x; }
__device__ __forceinline__ float sigmoidf(float x) { return 1.f / (1.f + expf(-x)); }

// ---------------- init: zero counts/fill/embp, compute Pvec ----------------

__global__ void zero_all_kernel(int* counts, int* fill, double* embp, int KN, int NEMBP,
                                const float* __restrict__ W1, const float* __restrict__ a_src1,
                                const float* __restrict__ a_dst1, float* Pvec, int D1) {
    int tid = blockIdx.x * blockDim.x + threadIdx.x;
    if (tid < KN) { counts[tid] = 0; fill[tid] = 0; }
    if (tid < NEMBP) embp[tid] = 0.0;
    if (blockIdx.x == 0 && threadIdx.x < 16 && D1 == 1) {
        int h = threadIdx.x & 7;
        const float* a = (threadIdx.x >= 8) ? a_dst1 : a_src1;
        float s = 0.f;
        for (int c = 0; c < 32; ++c) s += W1[h * 32 + c] * a[h * 32 + c];
        Pvec[threadIdx.x] = s;
    }
}

// ---------------- batched CSR build ----------------

__global__ void count_all_kernel(const int* __restrict__ ei, int E, int N,
                                 int* __restrict__ counts) {
    int k = blockIdx.y;
    int j = blockIdx.x * blockDim.x + threadIdx.x;
    if (j >= E + N) return;
    int d = (j < E) ? ei[(size_t)k * 2 * E + E + j] : (j - E);
    atomicAdd(&counts[(size_t)k * N + d], 1);
}

__global__ __launch_bounds__(1024) void scan_all_kernel(const int* __restrict__ counts,
                                                        int* __restrict__ row_ptr, int N) {
    int k = blockIdx.x;
    const int* cnt = counts + (size_t)k * N;
    int* rp = row_ptr + (size_t)k * (N + 1);
    __shared__ int part[1024];
    int t = threadIdx.x;
    int ipt = (N + 1023) >> 10;
    int begin = t * ipt;
    int end = begin + ipt; if (end > N) end = N;
    if (begin > N) begin = N;
    int s = 0;
    for (int i = begin; i < end; ++i) s += cnt[i];
    part[t] = s;
    __syncthreads();
    for (int d = 1; d < 1024; d <<= 1) {
        int v = 0;
        if (t >= d) v = part[t - d];
        __syncthreads();
        if (t >= d) part[t] += v;
        __syncthreads();
    }
    int run = (t == 0) ? 0 : part[t - 1];
    for (int i = begin; i < end; ++i) { rp[i] = run; run += cnt[i]; }
    if (t == 1023) rp[N] = part[1023];
}

__global__ void scatter_all_kernel(const int* __restrict__ ei, int E, int N,
                                   const int* __restrict__ row_ptr, int* __restrict__ fill,
                                   int* __restrict__ ein) {
    int k = blockIdx.y;
    int j = blockIdx.x * blockDim.x + threadIdx.x;
    if (j >= E + N) return;
    int s, d;
    if (j < E) { s = ei[(size_t)k * 2 * E + j]; d = ei[(size_t)k * 2 * E + E + j]; }
    else { s = j - E; d = s; }
    int pos = row_ptr[(size_t)k * (N + 1) + d] + atomicAdd(&fill[(size_t)k * N + d], 1);
    ein[(size_t)k * (E + N) + pos] = s;
}

// ---------------- layer-1 rank-1 GAT (D1 == 1) ----------------

__global__ __launch_bounds__(256) void agg1_all_kernel(const float* __restrict__ xs,
                                                       const float* __restrict__ P,
                                                       const int* __restrict__ row_ptr,
                                                       const int* __restrict__ ein,
                                                       const float* __restrict__ W1,
                                                       const float* __restrict__ b1,
                                                       float* __restrict__ bufB,
                                                       int N, int E2, int k0) {
    int kb = blockIdx.y;
    int k = k0 + kb;
    const float* x = xs + (size_t)k * N;
    const int* rp = row_ptr + (size_t)k * (N + 1);
    const int* ek = ein + (size_t)k * E2;
    float* out = bufB + (size_t)kb * N * 256;

    int n = blockIdx.x * 4 + (threadIdx.x >> 6);
    if (n >= N) return;
    int lane = threadIdx.x & 63;
    int e0 = rp[n], e1 = rp[n + 1];
    int h8 = lane & 7;
    float Ps = P[h8], Pd = P[8 + h8];
    float base = x[n] * Pd;

    float mx = -INFINITY;
    for (int i = e0 + (lane >> 3); i < e1; i += 8) {
        float xv = x[ek[i]];
        mx = fmaxf(mx, lrelu(xv * Ps + base));
    }
    mx = fmaxf(mx, __shfl_xor(mx, 8));
    mx = fmaxf(mx, __shfl_xor(mx, 16));
    mx = fmaxf(mx, __shfl_xor(mx, 32));

    float num = 0.f, den = 0.f;
    for (int i = e0 + (lane >> 3); i < e1; i += 8) {
        float xv = x[ek[i]];
        float w = expf(lrelu(xv * Ps + base) - mx);
        num += w * xv;
        den += w;
    }
    num += __shfl_xor(num, 8);  den += __shfl_xor(den, 8);
    num += __shfl_xor(num, 16); den += __shfl_xor(den, 16);
    num += __shfl_xor(num, 32); den += __shfl_xor(den, 32);
    float S = num / (den + 1e-16f);

    int hd = lane >> 3;
    float Sh = __shfl(S, hd);
    const float4 wv = *(const float4*)(W1 + lane * 4);
    const float4 bv = *(const float4*)(b1 + lane * 4);
    float4 o;
    o.x = fmaxf(Sh * wv.x + bv.x, 0.f);
    o.y = fmaxf(Sh * wv.y + bv.y, 0.f);
    o.z = fmaxf(Sh * wv.z + bv.z, 0.f);
    o.w = fmaxf(Sh * wv.w + bv.w, 0.f);
    *(float4*)(out + (size_t)n * 256 + lane * 4) = o;
}

// ---------------- generic layer-1 fallback (D1 != 1) ----------------

__global__ void h1_kernel(const float* __restrict__ x, const float* __restrict__ W,
                          float* __restrict__ h, int N, int D1) {
    int tid = blockIdx.x * blockDim.x + threadIdx.x;
    if (tid >= N * 256) return;
    int n = tid >> 8, j = tid & 255;
    float acc = 0.f;
    for (int d = 0; d < D1; ++d) acc += x[n * D1 + d] * W[d * 256 + j];
    h[tid] = acc;
}

// attention scalars: s_src/s_dst per (kb, n, h)
__global__ __launch_bounds__(256) void s_all_kernel(const float* __restrict__ bufA,
                                                    const float* __restrict__ a_src,
                                                    const float* __restrict__ a_dst,
                                                    float* __restrict__ s_src,
                                                    float* __restrict__ s_dst, int N) {
    int kb = blockIdx.y;
    int j = blockIdx.x * 256 + threadIdx.x;
    if (j >= N * 8) return;
    int n = j >> 3, hh = j & 7;
    const float* hp = bufA + (size_t)kb * N * 256 + (size_t)n * 256 + hh * 32;
    const float* as = a_src + hh * 32;
    const float* ad = a_dst + hh * 32;
    float ss = 0.f, sd = 0.f;
#pragma unroll
    for (int c = 0; c < 32; ++c) { float v = hp[c]; ss += v * as[c]; sd += v * ad[c]; }
    s_src[(size_t)kb * N * 8 + j] = ss;
    s_dst[(size_t)kb * N * 8 + j] = sd;
}

// fallback layer-1 full aggregation with output write
__global__ __launch_bounds__(256) void agg2_out_kernel(const float* __restrict__ h,
                                                       const float* __restrict__ s_src,
                                                       const float* __restrict__ s_dst,
                                                       const int* __restrict__ row_ptr,
                                                       const int* __restrict__ ein,
                                                       const float* __restrict__ bias,
                                                       float* __restrict__ out,
                                                       int N, int E2, int k0) {
    int k = k0;
    const int* rp = row_ptr + (size_t)k * (N + 1);
    const int* ek = ein + (size_t)k * E2;
    int n = blockIdx.x * 4 + (threadIdx.x >> 6);
    if (n >= N) return;
    int lane = threadIdx.x & 63;
    int e0 = rp[n], e1 = rp[n + 1];
    int h8 = lane & 7;
    float sd8 = s_dst[n * 8 + h8];

    float mx = -INFINITY;
    for (int i = e0 + (lane >> 3); i < e1; i += 8) {
        int s = ek[i];
        mx = fmaxf(mx, lrelu(s_src[s * 8 + h8] + sd8));
    }
    mx = fmaxf(mx, __shfl_xor(mx, 8));
    mx = fmaxf(mx, __shfl_xor(mx, 16));
    mx = fmaxf(mx, __shfl_xor(mx, 32));

    int hd = lane >> 3;
    float m = __shfl(mx, hd);
    float sdh = __shfl(sd8, hd);

    float den = 0.f;
    float4 acc = make_float4(0.f, 0.f, 0.f, 0.f);
    for (int i = e0; i < e1; ++i) {
        int s = ek[i];
        const float4 hv = *(const float4*)(h + (size_t)s * 256 + lane * 4);
        float w = expf(lrelu(s_src[s * 8 + hd] + sdh) - m);
        den += w;
        acc.x += w * hv.x; acc.y += w * hv.y; acc.z += w * hv.z; acc.w += w * hv.w;
    }
    float dE = den + 1e-16f;
    const float4 bv = *(const float4*)(bias + lane * 4);
    float4 o;
    o.x = fmaxf(acc.x / dE + bv.x, 0.f);
    o.y = fmaxf(acc.y / dE + bv.y, 0.f);
    o.z = fmaxf(acc.z / dE + bv.z, 0.f);
    o.w = fmaxf(acc.w / dE + bv.w, 0.f);
    *(float4*)(out + (size_t)n * 256 + lane * 4) = o;
}

// ---------------- layer-2 aggregation fused with f64 mean-pool ----------------
// 4 nodes/block. No output write; relu(out+b2) accumulated into embp[k][32][256] (f64).

__global__ __launch_bounds__(256) void agg2pool_kernel(const float* __restrict__ bufA,
                                                       const float* __restrict__ s_src,
                                                       const float* __restrict__ s_dst,
                                                       const int* __restrict__ row_ptr,
                                                       const int* __restrict__ ein,
                                                       const float* __restrict__ bias,
                                                       double* __restrict__ embp,
                                                       int N, int E2, int k0) {
    int kb = blockIdx.y;
    int k = k0 + kb;
    int w = threadIdx.x >> 6;
    int lane = threadIdx.x & 63;
    int n = blockIdx.x * 4 + w;
    bool active = (n < N);
    const float* h = bufA + (size_t)kb * N * 256;
    const float* ssrc = s_src + (size_t)kb * N * 8;
    const float* sdst = s_dst + (size_t)kb * N * 8;
    const int* rp = row_ptr + (size_t)k * (N + 1);
    const int* ek = ein + (size_t)k * E2;

    float4 o = make_float4(0.f, 0.f, 0.f, 0.f);
    if (active) {
        int e0 = rp[n], e1 = rp[n + 1];
        int h8 = lane & 7;
        float sd8 = sdst[n * 8 + h8];

        float mx = -INFINITY;
        for (int i = e0 + (lane >> 3); i < e1; i += 8) {
            int s = ek[i];
            mx = fmaxf(mx, lrelu(ssrc[s * 8 + h8] + sd8));
        }
        mx = fmaxf(mx, __shfl_xor(mx, 8));
        mx = fmaxf(mx, __shfl_xor(mx, 16));
        mx = fmaxf(mx, __shfl_xor(mx, 32));

        int hd = lane >> 3;
        float m = __shfl(mx, hd);
        float sdh = __shfl(sd8, hd);

        float den = 0.f;
        float4 acc = make_float4(0.f, 0.f, 0.f, 0.f);
        for (int i = e0; i < e1; ++i) {
            int s = ek[i];
            const float4 hv = *(const float4*)(h + (size_t)s * 256 + lane * 4);
            float wgt = expf(lrelu(ssrc[s * 8 + hd] + sdh) - m);
            den += wgt;
            acc.x += wgt * hv.x; acc.y += wgt * hv.y; acc.z += wgt * hv.z; acc.w += wgt * hv.w;
        }
        float dE = den + 1e-16f;
        const float4 bv = *(const float4*)(bias + lane * 4);
        o.x = fmaxf(acc.x / dE + bv.x, 0.f);
        o.y = fmaxf(acc.y / dE + bv.y, 0.f);
        o.z = fmaxf(acc.z / dE + bv.z, 0.f);
        o.w = fmaxf(acc.w / dE + bv.w, 0.f);
    }

    __shared__ double pe[4][256];
    pe[w][lane * 4 + 0] = (double)o.x;
    pe[w][lane * 4 + 1] = (double)o.y;
    pe[w][lane * 4 + 2] = (double)o.z;
    pe[w][lane * 4 + 3] = (double)o.w;
    __syncthreads();
    int tid = threadIdx.x;
    double s = pe[0][tid] + pe[1][tid] + pe[2][tid] + pe[3][tid];
    atomicAdd(&embp[((size_t)k * 32 + (blockIdx.x & 31)) * 256 + tid], s);
}

// ---------------- fp32 GEMM: C[M,256] = A[M,256] * W2[256,256], 128x128 tile ----------------

__global__ __launch_bounds__(256) void gemm_kernel(const float* __restrict__ A,
                                                   const float* __restrict__ B,
                                                   float* __restrict__ C, int M) {
    __shared__ float Ast[8][132];
    __shared__ float Bs[8][128];
    int tid = threadIdx.x;
    int bm = blockIdx.x, bn = blockIdx.y;
    int ty = tid >> 4, tx = tid & 15;
    int r0 = ty * 8, c0 = tx * 8;
    float acc[8][8] = {};
    int arow = tid >> 1, acol = (tid & 1) * 4;
    int brow = tid >> 5, bcol = (tid & 31) * 4;
    const float* Bbase = B + bn * 128;

    for (int kt = 0; kt < 256; kt += 8) {
        int gr = bm * 128 + arow;
        float4 av = (gr < M) ? *(const float4*)(A + (size_t)gr * 256 + kt + acol)
                             : make_float4(0.f, 0.f, 0.f, 0.f);
        Ast[acol + 0][arow] = av.x;
        Ast[acol + 1][arow] = av.y;
        Ast[acol + 2][arow] = av.z;
        Ast[acol + 3][arow] = av.w;
        *(float4*)&Bs[brow][bcol] = *(const float4*)(Bbase + (size_t)(kt + brow) * 256 + bcol);
        __syncthreads();
#pragma unroll
        for (int kk = 0; kk < 8; ++kk) {
            float4 a0 = *(const float4*)&Ast[kk][r0];
            float4 a1 = *(const float4*)&Ast[kk][r0 + 4];
            float4 b0 = *(const float4*)&Bs[kk][c0];
            float4 b1 = *(const float4*)&Bs[kk][c0 + 4];
            float ar[8] = {a0.x, a0.y, a0.z, a0.w, a1.x, a1.y, a1.z, a1.w};
            float br[8] = {b0.x, b0.y, b0.z, b0.w, b1.x, b1.y, b1.z, b1.w};
#pragma unroll
            for (int i2 = 0; i2 < 8; ++i2)
#pragma unroll
                for (int j2 = 0; j2 < 8; ++j2) acc[i2][j2] += ar[i2] * br[j2];
        }
        __syncthreads();
    }
#pragma unroll
    for (int i2 = 0; i2 < 8; ++i2) {
        int gm = bm * 128 + r0 + i2;
        if (gm < M) {
            *(float4*)(C + (size_t)gm * 256 + bn * 128 + c0) =
                make_float4(acc[i2][0], acc[i2][1], acc[i2][2], acc[i2][3]);
            *(float4*)(C + (size_t)gm * 256 + bn * 128 + c0 + 4) =
                make_float4(acc[i2][4], acc[i2][5], acc[i2][6], acc[i2][7]);
        }
    }
}

// ---------------- merge f64 pool partials -> f32 emb; zero LSTM flags ----------------

__global__ void merge_kernel(const double* __restrict__ embp, float* __restrict__ emb,
                             int* __restrict__ flags) {
    int k = blockIdx.x, c = threadIdx.x;
    double s = 0.0;
#pragma unroll
    for (int p = 0; p < 32; ++p) s += embp[((size_t)k * 32 + p) * 256 + c];
    emb[k * 256 + c] = (float)s;
    if (blockIdx.x == 0 && threadIdx.x < 2 * (KSTEPS + 1)) flags[threadIdx.x] = 0;
}

// ---------------- bidirectional LSTM: fused, 16 blocks/dir, cheap release/acquire sync ----

__global__ __launch_bounds__(256) void lstm_rec_kernel(
    const float* __restrict__ emb, float invN,
    const float* __restrict__ Wih_f, const float* __restrict__ Whh_f,
    const float* __restrict__ bih_f, const float* __restrict__ bhh_f,
    const float* __restrict__ Wih_b, const float* __restrict__ Whh_b,
    const float* __restrict__ bih_b, const float* __restrict__ bhh_b,
    float* __restrict__ hbuf,   // [2][K+1][256]
    int* __restrict__ flags,    // [2][K+1], pre-zeroed by merge_kernel
    float* __restrict__ out) {
    int dir = blockIdx.x >> 4;
    int seg = blockIdx.x & 15;
    const float* Wih = dir ? Wih_b : Wih_f;
    const float* Whh = dir ? Whh_b : Whh_f;
    const float* bih = dir ? bih_b : bih_f;
    const float* bhh = dir ? bhh_b : bhh_f;

    __shared__ float wh[64 * 256];        // 64 KB
    __shared__ float wi[64 * 256];        // 64 KB
    __shared__ float xs_s[KSTEPS * 256];  // 8 KB
    __shared__ float gx[KSTEPS][64];
    __shared__ float garr[64];
    __shared__ float hprev_s[256];
    int tid = threadIdx.x;

    for (int v = tid; v < 64 * 64; v += 256) {
        int lrow = v >> 6;
        int c4 = (v & 63) * 4;
        int grow = ((lrow >> 4) << 8) + seg * 16 + (lrow & 15);
        *(float4*)&wh[lrow * 256 + c4] = *(const float4*)(Whh + (size_t)grow * 256 + c4);
        *(float4*)&wi[lrow * 256 + c4] = *(const float4*)(Wih + (size_t)grow * 256 + c4);
    }
    for (int idx = tid; idx < KSTEPS * 256; idx += 256) xs_s[idx] = emb[idx] * invN;
    __syncthreads();

    // gx[step][lrow] = bias + dot(wi[lrow], x[step]) ; rotated k to stay conflict-free
    for (int d = tid; d < KSTEPS * 64; d += 256) {
        int st = d >> 6, lr = d & 63;
        const float* wr = &wi[lr << 8];
        const float* xr = &xs_s[st << 8];
        int r = (tid & 63) << 2;
        float acc = 0.f;
#pragma unroll 8
        for (int kk = 0; kk < 256; kk += 4) {
            int k2 = (kk + r) & 255;
            acc += wr[k2] * xr[k2] + wr[k2 + 1] * xr[k2 + 1] +
                   wr[k2 + 2] * xr[k2 + 2] + wr[k2 + 3] * xr[k2 + 3];
        }
        int grow = ((lr >> 4) << 8) + seg * 16 + (lr & 15);
        gx[st][lr] = acc + bih[grow] + bhh[grow];
    }

    int* flag = flags + dir * (KSTEPS + 1);
    float* hb = hbuf + dir * (KSTEPS + 1) * 256;

    if (tid < 16)
        __hip_atomic_store(&hb[seg * 16 + tid], 0.f, __ATOMIC_RELAXED, __HIP_MEMORY_SCOPE_AGENT);
    __syncthreads();  // implicit vmcnt-drain of this wave's stores
    if (tid == 0)
        __hip_atomic_fetch_add(&flag[0], 1, __ATOMIC_RELEASE, __HIP_MEMORY_SCOPE_AGENT);

    float c_reg = 0.f;

    for (int step = 0; step < KSTEPS; ++step) {
        if (tid == 0) {
            while (__hip_atomic_load(&flag[step], __ATOMIC_RELAXED, __HIP_MEMORY_SCOPE_AGENT) < 16) {
                __builtin_amdgcn_s_sleep(1);
            }
            (void)__hip_atomic_load(&flag[step], __ATOMIC_ACQUIRE, __HIP_MEMORY_SCOPE_AGENT);
        }
        __syncthreads();
        hprev_s[tid] = __hip_atomic_load(&hb[step * 256 + tid], __ATOMIC_RELAXED,
                                         __HIP_MEMORY_SCOPE_AGENT);
        __syncthreads();

        // 64 dots of length 256: 4 threads/dot
        int d = tid >> 2, p = tid & 3;
        const float* wr = &wh[(d << 8) + (p << 6)];
        const float* hr = &hprev_s[p << 6];
        int rot = tid & 63;
        float acc = 0.f;
#pragma unroll 8
        for (int k = 0; k < 64; ++k) {
            int k2 = (k + rot) & 63;
            acc += wr[k2] * hr[k2];
        }
        acc += __shfl_xor(acc, 1);
        acc += __shfl_xor(acc, 2);
        if (p == 0) garr[d] = acc;
        __syncthreads();

        if (tid < 16) {
            float ig = sigmoidf(garr[tid] + gx[step][tid]);
            float fg = sigmoidf(garr[16 + tid] + gx[step][16 + tid]);
            float gg = tanhf(garr[32 + tid] + gx[step][32 + tid]);
            float og = sigmoidf(garr[48 + tid] + gx[step][48 + tid]);
            float cn = fg * c_reg + ig * gg;
            c_reg = cn;
            float hn = og * tanhf(cn);
            __hip_atomic_store(&hb[(step + 1) * 256 + seg * 16 + tid], hn, __ATOMIC_RELAXED,
                               __HIP_MEMORY_SCOPE_AGENT);
        }
        __syncthreads();  // drains the tid<16 stores (per-wave vmcnt(0) before barrier)
        if (tid == 0)
            __hip_atomic_fetch_add(&flag[step + 1], 1, __ATOMIC_RELEASE, __HIP_MEMORY_SCOPE_AGENT);
    }

    if (tid < 16)
        out[dir * 256 + seg * 16 + tid] =
            __hip_atomic_load(&hb[KSTEPS * 256 + seg * 16 + tid], __ATOMIC_RELAXED,
                              __HIP_MEMORY_SCOPE_AGENT);
}

// ---------------- launch ----------------

extern "C" void kernel_launch(void* const* d_in, const int* in_sizes, int n_in,
                              void* d_out, int out_size, void* d_ws, size_t ws_size,
                              hipStream_t stream) {
    const float* xs = (const float*)d_in[0];
    const int* edge_index = (const int*)d_in[1];
    const float* W1 = (const float*)d_in[2];
    const float* a_src1 = (const float*)d_in[3];
    const float* a_dst1 = (const float*)d_in[4];
    const float* b1 = (const float*)d_in[5];
    const float* W2 = (const float*)d_in[6];
    const float* a_src2 = (const float*)d_in[7];
    const float* a_dst2 = (const float*)d_in[8];
    const float* b2 = (const float*)d_in[9];
    const float* Wih_f = (const float*)d_in[10];
    const float* Whh_f = (const float*)d_in[11];
    const float* bih_f = (const float*)d_in[12];
    const float* bhh_f = (const float*)d_in[13];
    const float* Wih_b = (const float*)d_in[14];
    const float* Whh_b = (const float*)d_in[15];
    const float* bih_b = (const float*)d_in[16];
    const float* bhh_b = (const float*)d_in[17];

    const int K = KSTEPS;
    int D1 = in_sizes[2] / D2;
    int N = in_sizes[0] / (K * D1);
    int E = in_sizes[1] / (2 * K);
    int E2 = E + N;

    auto al = [](size_t x) { return (x + 255) & ~(size_t)255; };
    size_t fixed_sz = al((size_t)K * N * 4)            // counts
                    + al((size_t)K * (N + 1) * 4)      // row_ptr
                    + al((size_t)K * N * 4)            // fill
                    + al((size_t)K * E2 * 4)           // ein
                    + al((size_t)K * 32 * 256 * 8)     // embp
                    + al((size_t)K * 256 * 4)          // emb
                    + al((size_t)2 * (K + 1) * 256 * 4)// hbuf
                    + al((size_t)2 * (K + 1) * 4)      // flags
                    + al(16 * 4);                      // Pvec
    int BK = 8;
    while (BK > 1) {
        size_t need = fixed_sz + 2 * al((size_t)BK * N * 8 * 4) + 2 * al((size_t)BK * N * 256 * 4);
        if (need <= ws_size) break;
        BK >>= 1;
    }

    char* w = (char*)d_ws;
    auto alloc = [&](size_t bytes) { char* p = w; w += (bytes + 255) & ~(size_t)255; return p; };
    int* counts = (int*)alloc((size_t)K * N * 4);
    int* row_ptr = (int*)alloc((size_t)K * (N + 1) * 4);
    int* fill = (int*)alloc((size_t)K * N * 4);
    int* ein = (int*)alloc((size_t)K * E2 * 4);
    double* embp = (double*)alloc((size_t)K * 32 * 256 * 8);
    float* emb = (float*)alloc((size_t)K * 256 * 4);
    float* hbuf = (float*)alloc((size_t)2 * (K + 1) * 256 * 4);
    int* flags = (int*)alloc((size_t)2 * (K + 1) * 4);
    float* Pvec = (float*)alloc(16 * 4);
    float* s_src = (float*)alloc((size_t)BK * N * 8 * 4);
    float* s_dst = (float*)alloc((size_t)BK * N * 8 * 4);
    float* bufA = (float*)alloc((size_t)BK * N * 256 * 4);
    float* bufB = (float*)alloc((size_t)BK * N * 256 * 4);

    int KN = K * N;
    int NEMBP = K * 32 * 256;
    int zblk = ((KN > NEMBP ? KN : NEMBP) + 255) / 256;
    zero_all_kernel<<<zblk, 256, 0, stream>>>(counts, fill, embp, KN, NEMBP,
                                              W1, a_src1, a_dst1, Pvec, D1);
    int eblk = (E2 + 255) / 256;
    count_all_kernel<<<dim3(eblk, K), 256, 0, stream>>>(edge_index, E, N, counts);
    scan_all_kernel<<<K, 1024, 0, stream>>>(counts, row_ptr, N);
    scatter_all_kernel<<<dim3(eblk, K), 256, 0, stream>>>(edge_index, E, N, row_ptr, fill, ein);

    int nblk4 = (N + 3) / 4;
    int sblk = (N * 8 + 255) / 256;
    for (int k0 = 0; k0 < K; k0 += BK) {
        int BKcur = (K - k0 < BK) ? (K - k0) : BK;
        if (D1 == 1) {
            agg1_all_kernel<<<dim3(nblk4, BKcur), 256, 0, stream>>>(
                xs, Pvec, row_ptr, ein, W1, b1, bufB, N, E2, k0);
            int M = BKcur * N;
            gemm_kernel<<<dim3((M + 127) / 128, 2), 256, 0, stream>>>(bufB, W2, bufA, M);
            s_all_kernel<<<dim3(sblk, BKcur), 256, 0, stream>>>(bufA, a_src2, a_dst2,
                                                                s_src, s_dst, N);
            agg2pool_kernel<<<dim3(nblk4, BKcur), 256, 0, stream>>>(
                bufA, s_src, s_dst, row_ptr, ein, b2, embp, N, E2, k0);
        } else {
            for (int kk = 0; kk < BKcur; ++kk) {
                int k = k0 + kk;
                const float* xk = xs + (size_t)k * N * D1;
                h1_kernel<<<(N * 256 + 255) / 256, 256, 0, stream>>>(xk, W1, bufA, N, D1);
                s_all_kernel<<<dim3(sblk, 1), 256, 0, stream>>>(bufA, a_src1, a_dst1,
                                                                s_src, s_dst, N);
                agg2_out_kernel<<<nblk4, 256, 0, stream>>>(bufA, s_src, s_dst, row_ptr, ein,
                                                           b1, bufB, N, E2, k);
                gemm_kernel<<<dim3((N + 127) / 128, 2), 256, 0, stream>>>(bufB, W2, bufA, N);
                s_all_kernel<<<dim3(sblk, 1), 256, 0, stream>>>(bufA, a_src2, a_dst2,
                                                                s_src, s_dst, N);
                agg2pool_kernel<<<dim3(nblk4, 1), 256, 0, stream>>>(
                    bufA, s_src, s_dst, row_ptr, ein, b2, embp, N, E2, k);
            }
        }
    }

    merge_kernel<<<K, 256, 0, stream>>>(embp, emb, flags);
    lstm_rec_kernel<<<32, 256, 0, stream>>>(emb, 1.f / (float)N,
                                            Wih_f, Whh_f, bih_f, bhh_f,
                                            Wih_b, Whh_b, bih_b, bhh_b,
                                            hbuf, flags, (float*)d_out);
}

// Round 5
// 613.416 us; speedup vs baseline: 3.0442x; 1.1082x over previous
//
#include <hip/hip_runtime.h>
#include <math.h>

#define H_HEADS 8
#define C_HID 32
#define D2 256
#define NEG_SLOPE 0.2f
#define KSTEPS 8

__device__ __forceinline__ float lrelu(float x) { return x < 0.f ? NEG_SLOPE * x : x; }
__device__ __forceinline__ float sigmoidf(float x) { return 1.f / (1.f + expf(-x)); }

// ---------------- init: zero counts/fill/embp, compute Pvec ----------------

__global__ void zero_all_kernel(int* counts, int* fill, double* embp, int KN, int NEMBP,
                                const float* __restrict__ W1, const float* __restrict__ a_src1,
                                const float* __restrict__ a_dst1, float* Pvec, int D1) {
    int tid = blockIdx.x * blockDim.x + threadIdx.x;
    if (tid < KN) { counts[tid] = 0; fill[tid] = 0; }
    if (tid < NEMBP) embp[tid] = 0.0;
    if (blockIdx.x == 0 && threadIdx.x < 16 && D1 == 1) {
        int h = threadIdx.x & 7;
        const float* a = (threadIdx.x >= 8) ? a_dst1 : a_src1;
        float s = 0.f;
        for (int c = 0; c < 32; ++c) s += W1[h * 32 + c] * a[h * 32 + c];
        Pvec[threadIdx.x] = s;
    }
}

// ---------------- batched CSR build (snapshot->XCD swizzled 1-D grids) ----------------

__global__ void count_all_kernel(const int* __restrict__ ei, int E, int N, int K,
                                 int* __restrict__ counts) {
    int bid = blockIdx.x;
    int k = bid % K;
    int jb = bid / K;
    int j = jb * blockDim.x + threadIdx.x;
    if (j >= E + N) return;
    int d = (j < E) ? ei[(size_t)k * 2 * E + E + j] : (j - E);
    atomicAdd(&counts[(size_t)k * N + d], 1);
}

__global__ __launch_bounds__(1024) void scan_all_kernel(const int* __restrict__ counts,
                                                        int* __restrict__ row_ptr, int N) {
    int k = blockIdx.x;
    const int* cnt = counts + (size_t)k * N;
    int* rp = row_ptr + (size_t)k * (N + 1);
    __shared__ int part[1024];
    int t = threadIdx.x;
    int ipt = (N + 1023) >> 10;
    int begin = t * ipt;
    int end = begin + ipt; if (end > N) end = N;
    if (begin > N) begin = N;
    int s = 0;
    for (int i = begin; i < end; ++i) s += cnt[i];
    part[t] = s;
    __syncthreads();
    for (int d = 1; d < 1024; d <<= 1) {
        int v = 0;
        if (t >= d) v = part[t - d];
        __syncthreads();
        if (t >= d) part[t] += v;
        __syncthreads();
    }
    int run = (t == 0) ? 0 : part[t - 1];
    for (int i = begin; i < end; ++i) { rp[i] = run; run += cnt[i]; }
    if (t == 1023) rp[N] = part[1023];
}

__global__ void scatter_all_kernel(const int* __restrict__ ei, int E, int N, int K,
                                   const int* __restrict__ row_ptr, int* __restrict__ fill,
                                   int* __restrict__ ein) {
    int bid = blockIdx.x;
    int k = bid % K;
    int jb = bid / K;
    int j = jb * blockDim.x + threadIdx.x;
    if (j >= E + N) return;
    int s, d;
    if (j < E) { s = ei[(size_t)k * 2 * E + j]; d = ei[(size_t)k * 2 * E + E + j]; }
    else { s = j - E; d = s; }
    int pos = row_ptr[(size_t)k * (N + 1) + d] + atomicAdd(&fill[(size_t)k * N + d], 1);
    ein[(size_t)k * (E + N) + pos] = s;
}

// ---------------- layer-1 rank-1 GAT (D1 == 1), snapshot->XCD swizzled ----------------

__global__ __launch_bounds__(256) void agg1_all_kernel(const float* __restrict__ xs,
                                                       const float* __restrict__ P,
                                                       const int* __restrict__ row_ptr,
                                                       const int* __restrict__ ein,
                                                       const float* __restrict__ W1,
                                                       const float* __restrict__ b1,
                                                       float* __restrict__ bufB,
                                                       int N, int E2, int k0, int BKcur) {
    int bid = blockIdx.x;
    int kb = bid % BKcur;
    int nb = bid / BKcur;
    int k = k0 + kb;
    const float* x = xs + (size_t)k * N;
    const int* rp = row_ptr + (size_t)k * (N + 1);
    const int* ek = ein + (size_t)k * E2;
    float* out = bufB + (size_t)kb * N * 256;

    int n = nb * 4 + (threadIdx.x >> 6);
    if (n >= N) return;
    int lane = threadIdx.x & 63;
    int e0 = rp[n], e1 = rp[n + 1];
    int h8 = lane & 7;
    float Ps = P[h8], Pd = P[8 + h8];
    float base = x[n] * Pd;

    float mx = -INFINITY;
    for (int i = e0 + (lane >> 3); i < e1; i += 8) {
        float xv = x[ek[i]];
        mx = fmaxf(mx, lrelu(xv * Ps + base));
    }
    mx = fmaxf(mx, __shfl_xor(mx, 8));
    mx = fmaxf(mx, __shfl_xor(mx, 16));
    mx = fmaxf(mx, __shfl_xor(mx, 32));

    float num = 0.f, den = 0.f;
    for (int i = e0 + (lane >> 3); i < e1; i += 8) {
        float xv = x[ek[i]];
        float w = expf(lrelu(xv * Ps + base) - mx);
        num += w * xv;
        den += w;
    }
    num += __shfl_xor(num, 8);  den += __shfl_xor(den, 8);
    num += __shfl_xor(num, 16); den += __shfl_xor(den, 16);
    num += __shfl_xor(num, 32); den += __shfl_xor(den, 32);
    float S = num / (den + 1e-16f);

    int hd = lane >> 3;
    float Sh = __shfl(S, hd);
    const float4 wv = *(const float4*)(W1 + lane * 4);
    const float4 bv = *(const float4*)(b1 + lane * 4);
    float4 o;
    o.x = fmaxf(Sh * wv.x + bv.x, 0.f);
    o.y = fmaxf(Sh * wv.y + bv.y, 0.f);
    o.z = fmaxf(Sh * wv.z + bv.z, 0.f);
    o.w = fmaxf(Sh * wv.w + bv.w, 0.f);
    *(float4*)(out + (size_t)n * 256 + lane * 4) = o;
}

// ---------------- generic layer-1 fallback (D1 != 1) ----------------

__global__ void h1_kernel(const float* __restrict__ x, const float* __restrict__ W,
                          float* __restrict__ h, int N, int D1) {
    int tid = blockIdx.x * blockDim.x + threadIdx.x;
    if (tid >= N * 256) return;
    int n = tid >> 8, j = tid & 255;
    float acc = 0.f;
    for (int d = 0; d < D1; ++d) acc += x[n * D1 + d] * W[d * 256 + j];
    h[tid] = acc;
}

// attention scalars: s_src/s_dst per (kb, n, h)
__global__ __launch_bounds__(256) void s_all_kernel(const float* __restrict__ bufA,
                                                    const float* __restrict__ a_src,
                                                    const float* __restrict__ a_dst,
                                                    float* __restrict__ s_src,
                                                    float* __restrict__ s_dst, int N) {
    int kb = blockIdx.y;
    int j = blockIdx.x * 256 + threadIdx.x;
    if (j >= N * 8) return;
    int n = j >> 3, hh = j & 7;
    const float* hp = bufA + (size_t)kb * N * 256 + (size_t)n * 256 + hh * 32;
    const float* as = a_src + hh * 32;
    const float* ad = a_dst + hh * 32;
    float ss = 0.f, sd = 0.f;
#pragma unroll
    for (int c = 0; c < 32; ++c) { float v = hp[c]; ss += v * as[c]; sd += v * ad[c]; }
    s_src[(size_t)kb * N * 8 + j] = ss;
    s_dst[(size_t)kb * N * 8 + j] = sd;
}

// fallback layer-1 full aggregation with output write
__global__ __launch_bounds__(256) void agg2_out_kernel(const float* __restrict__ h,
                                                       const float* __restrict__ s_src,
                                                       const float* __restrict__ s_dst,
                                                       const int* __restrict__ row_ptr,
                                                       const int* __restrict__ ein,
                                                       const float* __restrict__ bias,
                                                       float* __restrict__ out,
                                                       int N, int E2, int k0) {
    int k = k0;
    const int* rp = row_ptr + (size_t)k * (N + 1);
    const int* ek = ein + (size_t)k * E2;
    int n = blockIdx.x * 4 + (threadIdx.x >> 6);
    if (n >= N) return;
    int lane = threadIdx.x & 63;
    int e0 = rp[n], e1 = rp[n + 1];
    int h8 = lane & 7;
    float sd8 = s_dst[n * 8 + h8];

    float mx = -INFINITY;
    for (int i = e0 + (lane >> 3); i < e1; i += 8) {
        int s = ek[i];
        mx = fmaxf(mx, lrelu(s_src[s * 8 + h8] + sd8));
    }
    mx = fmaxf(mx, __shfl_xor(mx, 8));
    mx = fmaxf(mx, __shfl_xor(mx, 16));
    mx = fmaxf(mx, __shfl_xor(mx, 32));

    int hd = lane >> 3;
    float m = __shfl(mx, hd);
    float sdh = __shfl(sd8, hd);

    float den = 0.f;
    float4 acc = make_float4(0.f, 0.f, 0.f, 0.f);
    for (int i = e0; i < e1; ++i) {
        int s = ek[i];
        const float4 hv = *(const float4*)(h + (size_t)s * 256 + lane * 4);
        float w = expf(lrelu(s_src[s * 8 + hd] + sdh) - m);
        den += w;
        acc.x += w * hv.x; acc.y += w * hv.y; acc.z += w * hv.z; acc.w += w * hv.w;
    }
    float dE = den + 1e-16f;
    const float4 bv = *(const float4*)(bias + lane * 4);
    float4 o;
    o.x = fmaxf(acc.x / dE + bv.x, 0.f);
    o.y = fmaxf(acc.y / dE + bv.y, 0.f);
    o.z = fmaxf(acc.z / dE + bv.z, 0.f);
    o.w = fmaxf(acc.w / dE + bv.w, 0.f);
    *(float4*)(out + (size_t)n * 256 + lane * 4) = o;
}

// ---------------- layer-2 aggregation fused with f64 mean-pool ----------------
// 1-D grid, snapshot->XCD swizzle (kb = bid % BKcur). 4 nodes/block.
// Chunked pass 2: 8 edges x 8 heads of w computed with no lane redundancy
// (reuses pass-1 per-lane mx/sd8: head = lane&7, edge slot = lane>>3), then the
// gather sub-loop broadcasts w/src via __shfl. Values & accumulation order are
// bit-identical to the unchunked version.

__global__ __launch_bounds__(256) void agg2pool_kernel(const float* __restrict__ bufA,
                                                       const float* __restrict__ s_src,
                                                       const float* __restrict__ s_dst,
                                                       const int* __restrict__ row_ptr,
                                                       const int* __restrict__ ein,
                                                       const float* __restrict__ bias,
                                                       double* __restrict__ embp,
                                                       int N, int E2, int k0, int BKcur) {
    int bid = blockIdx.x;
    int kb = bid % BKcur;
    int nb = bid / BKcur;
    int k = k0 + kb;
    int w = threadIdx.x >> 6;
    int lane = threadIdx.x & 63;
    int n = nb * 4 + w;
    bool active = (n < N);
    const float* h = bufA + (size_t)kb * N * 256;
    const float* ssrc = s_src + (size_t)kb * N * 8;
    const float* sdst = s_dst + (size_t)kb * N * 8;
    const int* rp = row_ptr + (size_t)k * (N + 1);
    const int* ek = ein + (size_t)k * E2;

    float4 o = make_float4(0.f, 0.f, 0.f, 0.f);
    if (active) {
        int e0 = rp[n], e1 = rp[n + 1];
        int h8 = lane & 7;    // head for pass-1 / w-compute
        int es = lane >> 3;   // edge slot for w-compute
        int hd = lane >> 3;   // head for gather (cols lane*4..lane*4+3)
        float sd8 = sdst[n * 8 + h8];

        // pass 1: per-head max (8 edges x 8 heads per sweep)
        float mx = -INFINITY;
        for (int i = e0 + es; i < e1; i += 8) {
            int s = ek[i];
            mx = fmaxf(mx, lrelu(ssrc[s * 8 + h8] + sd8));
        }
        mx = fmaxf(mx, __shfl_xor(mx, 8));
        mx = fmaxf(mx, __shfl_xor(mx, 16));
        mx = fmaxf(mx, __shfl_xor(mx, 32));
        // mx now holds max for head (lane&7) on every lane.

        float den = 0.f;
        float4 acc = make_float4(0.f, 0.f, 0.f, 0.f);
        int hd4 = hd;  // source-lane base for broadcasts

        for (int c0 = e0; c0 < e1; c0 += 8) {
            // w-compute: this lane handles edge (c0+es), head (lane&7)
            int eI = c0 + es;
            bool valid = (eI < e1);
            int sA = ek[valid ? eI : e0];
            float wv = expf(lrelu(ssrc[sA * 8 + h8] + sd8) - mx);
            if (!valid) wv = 0.f;

            int jmax = e1 - c0; if (jmax > 8) jmax = 8;
#pragma unroll 8
            for (int j = 0; j < 8; ++j) {
                if (j >= jmax) break;
                int srcLane = (j << 3) + hd4;
                float wj = __shfl(wv, srcLane);
                int sj = __shfl(sA, srcLane);
                const float4 hv = *(const float4*)(h + (size_t)sj * 256 + lane * 4);
                den += wj;
                acc.x += wj * hv.x;
                acc.y += wj * hv.y;
                acc.z += wj * hv.z;
                acc.w += wj * hv.w;
            }
        }
        float dE = den + 1e-16f;
        const float4 bv = *(const float4*)(bias + lane * 4);
        o.x = fmaxf(acc.x / dE + bv.x, 0.f);
        o.y = fmaxf(acc.y / dE + bv.y, 0.f);
        o.z = fmaxf(acc.z / dE + bv.z, 0.f);
        o.w = fmaxf(acc.w / dE + bv.w, 0.f);
    }

    __shared__ double pe[4][256];
    pe[w][lane * 4 + 0] = (double)o.x;
    pe[w][lane * 4 + 1] = (double)o.y;
    pe[w][lane * 4 + 2] = (double)o.z;
    pe[w][lane * 4 + 3] = (double)o.w;
    __syncthreads();
    int tid = threadIdx.x;
    double s = pe[0][tid] + pe[1][tid] + pe[2][tid] + pe[3][tid];
    atomicAdd(&embp[((size_t)k * 32 + (nb & 31)) * 256 + tid], s);
}

// ---------------- fp32 GEMM: C[M,256] = A[M,256] * W2[256,256], 128x128 tile ----------------

__global__ __launch_bounds__(256) void gemm_kernel(const float* __restrict__ A,
                                                   const float* __restrict__ B,
                                                   float* __restrict__ C, int M) {
    __shared__ float Ast[8][132];
    __shared__ float Bs[8][128];
    int tid = threadIdx.x;
    int bm = blockIdx.x, bn = blockIdx.y;
    int ty = tid >> 4, tx = tid & 15;
    int r0 = ty * 8, c0 = tx * 8;
    float acc[8][8] = {};
    int arow = tid >> 1, acol = (tid & 1) * 4;
    int brow = tid >> 5, bcol = (tid & 31) * 4;
    const float* Bbase = B + bn * 128;

    for (int kt = 0; kt < 256; kt += 8) {
        int gr = bm * 128 + arow;
        float4 av = (gr < M) ? *(const float4*)(A + (size_t)gr * 256 + kt + acol)
                             : make_float4(0.f, 0.f, 0.f, 0.f);
        Ast[acol + 0][arow] = av.x;
        Ast[acol + 1][arow] = av.y;
        Ast[acol + 2][arow] = av.z;
        Ast[acol + 3][arow] = av.w;
        *(float4*)&Bs[brow][bcol] = *(const float4*)(Bbase + (size_t)(kt + brow) * 256 + bcol);
        __syncthreads();
#pragma unroll
        for (int kk = 0; kk < 8; ++kk) {
            float4 a0 = *(const float4*)&Ast[kk][r0];
            float4 a1 = *(const float4*)&Ast[kk][r0 + 4];
            float4 b0 = *(const float4*)&Bs[kk][c0];
            float4 b1 = *(const float4*)&Bs[kk][c0 + 4];
            float ar[8] = {a0.x, a0.y, a0.z, a0.w, a1.x, a1.y, a1.z, a1.w};
            float br[8] = {b0.x, b0.y, b0.z, b0.w, b1.x, b1.y, b1.z, b1.w};
#pragma unroll
            for (int i2 = 0; i2 < 8; ++i2)
#pragma unroll
                for (int j2 = 0; j2 < 8; ++j2) acc[i2][j2] += ar[i2] * br[j2];
        }
        __syncthreads();
    }
#pragma unroll
    for (int i2 = 0; i2 < 8; ++i2) {
        int gm = bm * 128 + r0 + i2;
        if (gm < M) {
            *(float4*)(C + (size_t)gm * 256 + bn * 128 + c0) =
                make_float4(acc[i2][0], acc[i2][1], acc[i2][2], acc[i2][3]);
            *(float4*)(C + (size_t)gm * 256 + bn * 128 + c0 + 4) =
                make_float4(acc[i2][4], acc[i2][5], acc[i2][6], acc[i2][7]);
        }
    }
}

// ---------------- merge f64 pool partials -> f32 emb; zero LSTM flags ----------------

__global__ void merge_kernel(const double* __restrict__ embp, float* __restrict__ emb,
                             int* __restrict__ flags) {
    int k = blockIdx.x, c = threadIdx.x;
    double s = 0.0;
#pragma unroll
    for (int p = 0; p < 32; ++p) s += embp[((size_t)k * 32 + p) * 256 + c];
    emb[k * 256 + c] = (float)s;
    if (blockIdx.x == 0 && threadIdx.x < 2 * (KSTEPS + 1)) flags[threadIdx.x] = 0;
}

// ---------------- bidirectional LSTM: fused, 16 blocks/dir, cheap release/acquire sync ----

__global__ __launch_bounds__(256) void lstm_rec_kernel(
    const float* __restrict__ emb, float invN,
    const float* __restrict__ Wih_f, const float* __restrict__ Whh_f,
    const float* __restrict__ bih_f, const float* __restrict__ bhh_f,
    const float* __restrict__ Wih_b, const float* __restrict__ Whh_b,
    const float* __restrict__ bih_b, const float* __restrict__ bhh_b,
    float* __restrict__ hbuf,   // [2][K+1][256]
    int* __restrict__ flags,    // [2][K+1], pre-zeroed by merge_kernel
    float* __restrict__ out) {
    int dir = blockIdx.x >> 4;
    int seg = blockIdx.x & 15;
    const float* Wih = dir ? Wih_b : Wih_f;
    const float* Whh = dir ? Whh_b : Whh_f;
    const float* bih = dir ? bih_b : bih_f;
    const float* bhh = dir ? bhh_b : bhh_f;

    __shared__ float wh[64 * 256];        // 64 KB
    __shared__ float wi[64 * 256];        // 64 KB
    __shared__ float xs_s[KSTEPS * 256];  // 8 KB
    __shared__ float gx[KSTEPS][64];
    __shared__ float garr[64];
    __shared__ float hprev_s[256];
    int tid = threadIdx.x;

    for (int v = tid; v < 64 * 64; v += 256) {
        int lrow = v >> 6;
        int c4 = (v & 63) * 4;
        int grow = ((lrow >> 4) << 8) + seg * 16 + (lrow & 15);
        *(float4*)&wh[lrow * 256 + c4] = *(const float4*)(Whh + (size_t)grow * 256 + c4);
        *(float4*)&wi[lrow * 256 + c4] = *(const float4*)(Wih + (size_t)grow * 256 + c4);
    }
    for (int idx = tid; idx < KSTEPS * 256; idx += 256) xs_s[idx] = emb[idx] * invN;
    __syncthreads();

    for (int d = tid; d < KSTEPS * 64; d += 256) {
        int st = d >> 6, lr = d & 63;
        const float* wr = &wi[lr << 8];
        const float* xr = &xs_s[st << 8];
        int r = (tid & 63) << 2;
        float acc = 0.f;
#pragma unroll 8
        for (int kk = 0; kk < 256; kk += 4) {
            int k2 = (kk + r) & 255;
            acc += wr[k2] * xr[k2] + wr[k2 + 1] * xr[k2 + 1] +
                   wr[k2 + 2] * xr[k2 + 2] + wr[k2 + 3] * xr[k2 + 3];
        }
        int grow = ((lr >> 4) << 8) + seg * 16 + (lr & 15);
        gx[st][lr] = acc + bih[grow] + bhh[grow];
    }

    int* flag = flags + dir * (KSTEPS + 1);
    float* hb = hbuf + dir * (KSTEPS + 1) * 256;

    if (tid < 16)
        __hip_atomic_store(&hb[seg * 16 + tid], 0.f, __ATOMIC_RELAXED, __HIP_MEMORY_SCOPE_AGENT);
    __syncthreads();
    if (tid == 0)
        __hip_atomic_fetch_add(&flag[0], 1, __ATOMIC_RELEASE, __HIP_MEMORY_SCOPE_AGENT);

    float c_reg = 0.f;

    for (int step = 0; step < KSTEPS; ++step) {
        if (tid == 0) {
            while (__hip_atomic_load(&flag[step], __ATOMIC_RELAXED, __HIP_MEMORY_SCOPE_AGENT) < 16) {
                __builtin_amdgcn_s_sleep(1);
            }
            (void)__hip_atomic_load(&flag[step], __ATOMIC_ACQUIRE, __HIP_MEMORY_SCOPE_AGENT);
        }
        __syncthreads();
        hprev_s[tid] = __hip_atomic_load(&hb[step * 256 + tid], __ATOMIC_RELAXED,
                                         __HIP_MEMORY_SCOPE_AGENT);
        __syncthreads();

        int d = tid >> 2, p = tid & 3;
        const float* wr = &wh[(d << 8) + (p << 6)];
        const float* hr = &hprev_s[p << 6];
        int rot = tid & 63;
        float acc = 0.f;
#pragma unroll 8
        for (int k = 0; k < 64; ++k) {
            int k2 = (k + rot) & 63;
            acc += wr[k2] * hr[k2];
        }
        acc += __shfl_xor(acc, 1);
        acc += __shfl_xor(acc, 2);
        if (p == 0) garr[d] = acc;
        __syncthreads();

        if (tid < 16) {
            float ig = sigmoidf(garr[tid] + gx[step][tid]);
            float fg = sigmoidf(garr[16 + tid] + gx[step][16 + tid]);
            float gg = tanhf(garr[32 + tid] + gx[step][32 + tid]);
            float og = sigmoidf(garr[48 + tid] + gx[step][48 + tid]);
            float cn = fg * c_reg + ig * gg;
            c_reg = cn;
            float hn = og * tanhf(cn);
            __hip_atomic_store(&hb[(step + 1) * 256 + seg * 16 + tid], hn, __ATOMIC_RELAXED,
                               __HIP_MEMORY_SCOPE_AGENT);
        }
        __syncthreads();
        if (tid == 0)
            __hip_atomic_fetch_add(&flag[step + 1], 1, __ATOMIC_RELEASE, __HIP_MEMORY_SCOPE_AGENT);
    }

    if (tid < 16)
        out[dir * 256 + seg * 16 + tid] =
            __hip_atomic_load(&hb[KSTEPS * 256 + seg * 16 + tid], __ATOMIC_RELAXED,
                              __HIP_MEMORY_SCOPE_AGENT);
}

// ---------------- launch ----------------

extern "C" void kernel_launch(void* const* d_in, const int* in_sizes, int n_in,
                              void* d_out, int out_size, void* d_ws, size_t ws_size,
                              hipStream_t stream) {
    const float* xs = (const float*)d_in[0];
    const int* edge_index = (const int*)d_in[1];
    const float* W1 = (const float*)d_in[2];
    const float* a_src1 = (const float*)d_in[3];
    const float* a_dst1 = (const float*)d_in[4];
    const float* b1 = (const float*)d_in[5];
    const float* W2 = (const float*)d_in[6];
    const float* a_src2 = (const float*)d_in[7];
    const float* a_dst2 = (const float*)d_in[8];
    const float* b2 = (const float*)d_in[9];
    const float* Wih_f = (const float*)d_in[10];
    const float* Whh_f = (const float*)d_in[11];
    const float* bih_f = (const float*)d_in[12];
    const float* bhh_f = (const float*)d_in[13];
    const float* Wih_b = (const float*)d_in[14];
    const float* Whh_b = (const float*)d_in[15];
    const float* bih_b = (const float*)d_in[16];
    const float* bhh_b = (const float*)d_in[17];

    const int K = KSTEPS;
    int D1 = in_sizes[2] / D2;
    int N = in_sizes[0] / (K * D1);
    int E = in_sizes[1] / (2 * K);
    int E2 = E + N;

    auto al = [](size_t x) { return (x + 255) & ~(size_t)255; };
    size_t fixed_sz = al((size_t)K * N * 4)
                    + al((size_t)K * (N + 1) * 4)
                    + al((size_t)K * N * 4)
                    + al((size_t)K * E2 * 4)
                    + al((size_t)K * 32 * 256 * 8)
                    + al((size_t)K * 256 * 4)
                    + al((size_t)2 * (K + 1) * 256 * 4)
                    + al((size_t)2 * (K + 1) * 4)
                    + al(16 * 4);
    int BK = 8;
    while (BK > 1) {
        size_t need = fixed_sz + 2 * al((size_t)BK * N * 8 * 4) + 2 * al((size_t)BK * N * 256 * 4);
        if (need <= ws_size) break;
        BK >>= 1;
    }

    char* w = (char*)d_ws;
    auto alloc = [&](size_t bytes) { char* p = w; w += (bytes + 255) & ~(size_t)255; return p; };
    int* counts = (int*)alloc((size_t)K * N * 4);
    int* row_ptr = (int*)alloc((size_t)K * (N + 1) * 4);
    int* fill = (int*)alloc((size_t)K * N * 4);
    int* ein = (int*)alloc((size_t)K * E2 * 4);
    double* embp = (double*)alloc((size_t)K * 32 * 256 * 8);
    float* emb = (float*)alloc((size_t)K * 256 * 4);
    float* hbuf = (float*)alloc((size_t)2 * (K + 1) * 256 * 4);
    int* flags = (int*)alloc((size_t)2 * (K + 1) * 4);
    float* Pvec = (float*)alloc(16 * 4);
    float* s_src = (float*)alloc((size_t)BK * N * 8 * 4);
    float* s_dst = (float*)alloc((size_t)BK * N * 8 * 4);
    float* bufA = (float*)alloc((size_t)BK * N * 256 * 4);
    float* bufB = (float*)alloc((size_t)BK * N * 256 * 4);

    int KN = K * N;
    int NEMBP = K * 32 * 256;
    int zblk = ((KN > NEMBP ? KN : NEMBP) + 255) / 256;
    zero_all_kernel<<<zblk, 256, 0, stream>>>(counts, fill, embp, KN, NEMBP,
                                              W1, a_src1, a_dst1, Pvec, D1);
    int eblk = (E2 + 255) / 256;
    count_all_kernel<<<eblk * K, 256, 0, stream>>>(edge_index, E, N, K, counts);
    scan_all_kernel<<<K, 1024, 0, stream>>>(counts, row_ptr, N);
    scatter_all_kernel<<<eblk * K, 256, 0, stream>>>(edge_index, E, N, K, row_ptr, fill, ein);

    int nblk4 = (N + 3) / 4;
    int sblk = (N * 8 + 255) / 256;
    for (int k0 = 0; k0 < K; k0 += BK) {
        int BKcur = (K - k0 < BK) ? (K - k0) : BK;
        if (D1 == 1) {
            agg1_all_kernel<<<nblk4 * BKcur, 256, 0, stream>>>(
                xs, Pvec, row_ptr, ein, W1, b1, bufB, N, E2, k0, BKcur);
            int M = BKcur * N;
            gemm_kernel<<<dim3((M + 127) / 128, 2), 256, 0, stream>>>(bufB, W2, bufA, M);
            s_all_kernel<<<dim3(sblk, BKcur), 256, 0, stream>>>(bufA, a_src2, a_dst2,
                                                                s_src, s_dst, N);
            agg2pool_kernel<<<nblk4 * BKcur, 256, 0, stream>>>(
                bufA, s_src, s_dst, row_ptr, ein, b2, embp, N, E2, k0, BKcur);
        } else {
            for (int kk = 0; kk < BKcur; ++kk) {
                int k = k0 + kk;
                const float* xk = xs + (size_t)k * N * D1;
                h1_kernel<<<(N * 256 + 255) / 256, 256, 0, stream>>>(xk, W1, bufA, N, D1);
                s_all_kernel<<<dim3(sblk, 1), 256, 0, stream>>>(bufA, a_src1, a_dst1,
                                                                s_src, s_dst, N);
                agg2_out_kernel<<<nblk4, 256, 0, stream>>>(bufA, s_src, s_dst, row_ptr, ein,
                                                           b1, bufB, N, E2, k);
                gemm_kernel<<<dim3((N + 127) / 128, 2), 256, 0, stream>>>(bufB, W2, bufA, N);
                s_all_kernel<<<dim3(sblk, 1), 256, 0, stream>>>(bufA, a_src2, a_dst2,
                                                                s_src, s_dst, N);
                agg2pool_kernel<<<nblk4, 256, 0, stream>>>(
                    bufA, s_src, s_dst, row_ptr, ein, b2, embp, N, E2, k, 1);
            }
        }
    }

    merge_kernel<<<K, 256, 0, stream>>>(embp, emb, flags);
    lstm_rec_kernel<<<32, 256, 0, stream>>>(emb, 1.f / (float)N,
                                            Wih_f, Whh_f, bih_f, bhh_f,
                                            Wih_b, Whh_b, bih_b, bhh_b,
                                            hbuf, flags, (float*)d_out);
}

// Round 7
// 582.778 us; speedup vs baseline: 3.2043x; 1.0526x over previous
//
#include <hip/hip_runtime.h>
#include <math.h>

#define H_HEADS 8
#define C_HID 32
#define D2 256
#define NEG_SLOPE 0.2f
#define KSTEPS 8

__device__ __forceinline__ float lrelu(float x) { return x < 0.f ? NEG_SLOPE * x : x; }
__device__ __forceinline__ float sigmoidf(float x) { return 1.f / (1.f + expf(-x)); }

// ---------------- init: zero counts/fill/embp, compute Pvec ----------------

__global__ void zero_all_kernel(int* counts, int* fill, double* embp, int KN, int NEMBP,
                                const float* __restrict__ W1, const float* __restrict__ a_src1,
                                const float* __restrict__ a_dst1, float* Pvec, int D1) {
    int tid = blockIdx.x * blockDim.x + threadIdx.x;
    if (tid < KN) { counts[tid] = 0; fill[tid] = 0; }
    if (tid < NEMBP) embp[tid] = 0.0;
    if (blockIdx.x == 0 && threadIdx.x < 16 && D1 == 1) {
        int h = threadIdx.x & 7;
        const float* a = (threadIdx.x >= 8) ? a_dst1 : a_src1;
        float s = 0.f;
        for (int c = 0; c < 32; ++c) s += W1[h * 32 + c] * a[h * 32 + c];
        Pvec[threadIdx.x] = s;
    }
}

// ---------------- batched CSR build (snapshot->XCD swizzled 1-D grids) ----------------

__global__ void count_all_kernel(const int* __restrict__ ei, int E, int N, int K,
                                 int* __restrict__ counts) {
    int bid = blockIdx.x;
    int k = bid % K;
    int jb = bid / K;
    int j = jb * blockDim.x + threadIdx.x;
    if (j >= E + N) return;
    int d = (j < E) ? ei[(size_t)k * 2 * E + E + j] : (j - E);
    atomicAdd(&counts[(size_t)k * N + d], 1);
}

__global__ __launch_bounds__(1024) void scan_all_kernel(const int* __restrict__ counts,
                                                        int* __restrict__ row_ptr, int N) {
    int k = blockIdx.x;
    const int* cnt = counts + (size_t)k * N;
    int* rp = row_ptr + (size_t)k * (N + 1);
    __shared__ int part[1024];
    int t = threadIdx.x;
    int ipt = (N + 1023) >> 10;
    int begin = t * ipt;
    int end = begin + ipt; if (end > N) end = N;
    if (begin > N) begin = N;
    int s = 0;
    for (int i = begin; i < end; ++i) s += cnt[i];
    part[t] = s;
    __syncthreads();
    for (int d = 1; d < 1024; d <<= 1) {
        int v = 0;
        if (t >= d) v = part[t - d];
        __syncthreads();
        if (t >= d) part[t] += v;
        __syncthreads();
    }
    int run = (t == 0) ? 0 : part[t - 1];
    for (int i = begin; i < end; ++i) { rp[i] = run; run += cnt[i]; }
    if (t == 1023) rp[N] = part[1023];
}

__global__ void scatter_all_kernel(const int* __restrict__ ei, int E, int N, int K,
                                   const int* __restrict__ row_ptr, int* __restrict__ fill,
                                   int* __restrict__ ein) {
    int bid = blockIdx.x;
    int k = bid % K;
    int jb = bid / K;
    int j = jb * blockDim.x + threadIdx.x;
    if (j >= E + N) return;
    int s, d;
    if (j < E) { s = ei[(size_t)k * 2 * E + j]; d = ei[(size_t)k * 2 * E + E + j]; }
    else { s = j - E; d = s; }
    int pos = row_ptr[(size_t)k * (N + 1) + d] + atomicAdd(&fill[(size_t)k * N + d], 1);
    ein[(size_t)k * (E + N) + pos] = s;
}

// ---------------- layer-1 rank-1 GAT (D1 == 1): writes S[n][8] only ----------------

__global__ __launch_bounds__(256) void agg1s_all_kernel(const float* __restrict__ xs,
                                                        const float* __restrict__ P,
                                                        const int* __restrict__ row_ptr,
                                                        const int* __restrict__ ein,
                                                        float* __restrict__ Sbuf,
                                                        int N, int E2, int k0, int BKcur) {
    int bid = blockIdx.x;
    int kb = bid % BKcur;
    int nb = bid / BKcur;
    int k = k0 + kb;
    const float* x = xs + (size_t)k * N;
    const int* rp = row_ptr + (size_t)k * (N + 1);
    const int* ek = ein + (size_t)k * E2;

    int n = nb * 4 + (threadIdx.x >> 6);
    if (n >= N) return;
    int lane = threadIdx.x & 63;
    int e0 = rp[n], e1 = rp[n + 1];
    int h8 = lane & 7;
    float Ps = P[h8], Pd = P[8 + h8];
    float base = x[n] * Pd;

    float mx = -INFINITY;
    for (int i = e0 + (lane >> 3); i < e1; i += 8) {
        float xv = x[ek[i]];
        mx = fmaxf(mx, lrelu(xv * Ps + base));
    }
    mx = fmaxf(mx, __shfl_xor(mx, 8));
    mx = fmaxf(mx, __shfl_xor(mx, 16));
    mx = fmaxf(mx, __shfl_xor(mx, 32));

    float num = 0.f, den = 0.f;
    for (int i = e0 + (lane >> 3); i < e1; i += 8) {
        float xv = x[ek[i]];
        float w = expf(lrelu(xv * Ps + base) - mx);
        num += w * xv;
        den += w;
    }
    num += __shfl_xor(num, 8);  den += __shfl_xor(den, 8);
    num += __shfl_xor(num, 16); den += __shfl_xor(den, 16);
    num += __shfl_xor(num, 32); den += __shfl_xor(den, 32);
    float S = num / (den + 1e-16f);

    if (lane < 8) Sbuf[((size_t)kb * N + n) * 8 + lane] = S;
}

// ---------------- generic layer-1 fallback (D1 != 1) ----------------

__global__ void h1_kernel(const float* __restrict__ x, const float* __restrict__ W,
                          float* __restrict__ h, int N, int D1) {
    int tid = blockIdx.x * blockDim.x + threadIdx.x;
    if (tid >= N * 256) return;
    int n = tid >> 8, j = tid & 255;
    float acc = 0.f;
    for (int d = 0; d < D1; ++d) acc += x[n * D1 + d] * W[d * 256 + j];
    h[tid] = acc;
}

// attention scalars: s_src/s_dst per (kb, n, h)
__global__ __launch_bounds__(256) void s_all_kernel(const float* __restrict__ bufA,
                                                    const float* __restrict__ a_src,
                                                    const float* __restrict__ a_dst,
                                                    float* __restrict__ s_src,
                                                    float* __restrict__ s_dst, int N) {
    int kb = blockIdx.y;
    int j = blockIdx.x * 256 + threadIdx.x;
    if (j >= N * 8) return;
    int n = j >> 3, hh = j & 7;
    const float* hp = bufA + (size_t)kb * N * 256 + (size_t)n * 256 + hh * 32;
    const float* as = a_src + hh * 32;
    const float* ad = a_dst + hh * 32;
    float ss = 0.f, sd = 0.f;
#pragma unroll
    for (int c = 0; c < 32; ++c) { float v = hp[c]; ss += v * as[c]; sd += v * ad[c]; }
    s_src[(size_t)kb * N * 8 + j] = ss;
    s_dst[(size_t)kb * N * 8 + j] = sd;
}

// fallback layer-1 full aggregation with output write
__global__ __launch_bounds__(256) void agg2_out_kernel(const float* __restrict__ h,
                                                       const float* __restrict__ s_src,
                                                       const float* __restrict__ s_dst,
                                                       const int* __restrict__ row_ptr,
                                                       const int* __restrict__ ein,
                                                       const float* __restrict__ bias,
                                                       float* __restrict__ out,
                                                       int N, int E2, int k0) {
    int k = k0;
    const int* rp = row_ptr + (size_t)k * (N + 1);
    const int* ek = ein + (size_t)k * E2;
    int n = blockIdx.x * 4 + (threadIdx.x >> 6);
    if (n >= N) return;
    int lane = threadIdx.x & 63;
    int e0 = rp[n], e1 = rp[n + 1];
    int h8 = lane & 7;
    float sd8 = s_dst[n * 8 + h8];

    float mx = -INFINITY;
    for (int i = e0 + (lane >> 3); i < e1; i += 8) {
        int s = ek[i];
        mx = fmaxf(mx, lrelu(s_src[s * 8 + h8] + sd8));
    }
    mx = fmaxf(mx, __shfl_xor(mx, 8));
    mx = fmaxf(mx, __shfl_xor(mx, 16));
    mx = fmaxf(mx, __shfl_xor(mx, 32));

    int hd = lane >> 3;
    float m = __shfl(mx, hd);
    float sdh = __shfl(sd8, hd);

    float den = 0.f;
    float4 acc = make_float4(0.f, 0.f, 0.f, 0.f);
    for (int i = e0; i < e1; ++i) {
        int s = ek[i];
        const float4 hv = *(const float4*)(h + (size_t)s * 256 + lane * 4);
        float w = expf(lrelu(s_src[s * 8 + hd] + sdh) - m);
        den += w;
        acc.x += w * hv.x; acc.y += w * hv.y; acc.z += w * hv.z; acc.w += w * hv.w;
    }
    float dE = den + 1e-16f;
    const float4 bv = *(const float4*)(bias + lane * 4);
    float4 o;
    o.x = fmaxf(acc.x / dE + bv.x, 0.f);
    o.y = fmaxf(acc.y / dE + bv.y, 0.f);
    o.z = fmaxf(acc.z / dE + bv.z, 0.f);
    o.w = fmaxf(acc.w / dE + bv.w, 0.f);
    *(float4*)(out + (size_t)n * 256 + lane * 4) = o;
}

// ---------------- layer-2 aggregation fused with f64 mean-pool ----------------

__global__ __launch_bounds__(256) void agg2pool_kernel(const float* __restrict__ bufA,
                                                       const float* __restrict__ s_src,
                                                       const float* __restrict__ s_dst,
                                                       const int* __restrict__ row_ptr,
                                                       const int* __restrict__ ein,
                                                       const float* __restrict__ bias,
                                                       double* __restrict__ embp,
                                                       int N, int E2, int k0, int BKcur) {
    int bid = blockIdx.x;
    int kb = bid % BKcur;
    int nb = bid / BKcur;
    int k = k0 + kb;
    int w = threadIdx.x >> 6;
    int lane = threadIdx.x & 63;
    int n = nb * 4 + w;
    bool active = (n < N);
    const float* h = bufA + (size_t)kb * N * 256;
    const float* ssrc = s_src + (size_t)kb * N * 8;
    const float* sdst = s_dst + (size_t)kb * N * 8;
    const int* rp = row_ptr + (size_t)k * (N + 1);
    const int* ek = ein + (size_t)k * E2;

    float4 o = make_float4(0.f, 0.f, 0.f, 0.f);
    if (active) {
        int e0 = rp[n], e1 = rp[n + 1];
        int h8 = lane & 7;
        int es = lane >> 3;
        int hd = lane >> 3;
        float sd8 = sdst[n * 8 + h8];

        float mx = -INFINITY;
        for (int i = e0 + es; i < e1; i += 8) {
            int s = ek[i];
            mx = fmaxf(mx, lrelu(ssrc[s * 8 + h8] + sd8));
        }
        mx = fmaxf(mx, __shfl_xor(mx, 8));
        mx = fmaxf(mx, __shfl_xor(mx, 16));
        mx = fmaxf(mx, __shfl_xor(mx, 32));

        float den = 0.f;
        float4 acc = make_float4(0.f, 0.f, 0.f, 0.f);
        int hd4 = hd;

        for (int c0 = e0; c0 < e1; c0 += 8) {
            int eI = c0 + es;
            bool valid = (eI < e1);
            int sA = ek[valid ? eI : e0];
            float wv = expf(lrelu(ssrc[sA * 8 + h8] + sd8) - mx);
            if (!valid) wv = 0.f;

            int jmax = e1 - c0; if (jmax > 8) jmax = 8;
#pragma unroll 8
            for (int j = 0; j < 8; ++j) {
                if (j >= jmax) break;
                int srcLane = (j << 3) + hd4;
                float wj = __shfl(wv, srcLane);
                int sj = __shfl(sA, srcLane);
                const float4 hv = *(const float4*)(h + (size_t)sj * 256 + lane * 4);
                den += wj;
                acc.x += wj * hv.x;
                acc.y += wj * hv.y;
                acc.z += wj * hv.z;
                acc.w += wj * hv.w;
            }
        }
        float dE = den + 1e-16f;
        const float4 bv = *(const float4*)(bias + lane * 4);
        o.x = fmaxf(acc.x / dE + bv.x, 0.f);
        o.y = fmaxf(acc.y / dE + bv.y, 0.f);
        o.z = fmaxf(acc.z / dE + bv.z, 0.f);
        o.w = fmaxf(acc.w / dE + bv.w, 0.f);
    }

    __shared__ double pe[4][256];
    pe[w][lane * 4 + 0] = (double)o.x;
    pe[w][lane * 4 + 1] = (double)o.y;
    pe[w][lane * 4 + 2] = (double)o.z;
    pe[w][lane * 4 + 3] = (double)o.w;
    __syncthreads();
    int tid = threadIdx.x;
    double s = pe[0][tid] + pe[1][tid] + pe[2][tid] + pe[3][tid];
    atomicAdd(&embp[((size_t)k * 32 + (nb & 31)) * 256 + tid], s);
}

// ---------------- fused rank-1-A fp32 GEMM: C[M,256] = relu(S.W1+b1)[M,256] * W2 ----------------
// 128x128 tile, K-step 16, wave = 8x8 lanes on a 64x64 quadrant (2-way LDS reads, free).
// A-tile is built in LDS from S (8 floats/row), W1, b1 — no global A operand.

__global__ __launch_bounds__(256) void gemm_fused_kernel(const float* __restrict__ S,
                                                         const float* __restrict__ W1,
                                                         const float* __restrict__ bias1,
                                                         const float* __restrict__ B,
                                                         float* __restrict__ C, int M) {
    __shared__ float Ast[16][132];
    __shared__ float Bs[16][132];
    __shared__ float w1s[256], b1s[256];
    __shared__ float Ss[128 * 8];
    int tid = threadIdx.x;
    int bm = blockIdx.x, bn = blockIdx.y;

    w1s[tid] = W1[tid];
    b1s[tid] = bias1[tid];
    // stage S rows for this block (128 rows x 8): 1024 floats, 4 per thread
    {
        int base = bm * 128 * 8 + tid * 4;
        float4 sv = make_float4(0.f, 0.f, 0.f, 0.f);
        if (bm * 128 + (tid * 4) / 8 < M) {
            sv = *(const float4*)(S + base);
        }
        *(float4*)&Ss[tid * 4] = sv;
    }

    int arow = tid >> 1;            // 0..127 (A row within tile)
    int kgrp = (tid & 1) * 8;       // 0 or 8
    bool rowvalid = (bm * 128 + arow < M);

    int brow = tid >> 4;            // 0..15
    int bcol = (tid & 15) * 8;      // 0..120
    const float* Bbase = B + bn * 128;

    int w = tid >> 6, lane = tid & 63;
    int qr = (w >> 1) * 64, qc = (w & 1) * 64;
    int ty = lane >> 3, tx = lane & 7;
    int r0 = qr + ty * 8, c0 = qc + tx * 8;
    float acc[8][8] = {};

    __syncthreads();

    for (int kt = 0; kt < 256; kt += 16) {
        // build A-tile (transposed) from S
        float sh = Ss[arow * 8 + (kt >> 5)];
#pragma unroll
        for (int j = 0; j < 8; ++j) {
            int kk = kgrp + j;
            float a = fmaxf(fmaf(sh, w1s[kt + kk], b1s[kt + kk]), 0.f);
            Ast[kk][arow] = rowvalid ? a : 0.f;
        }
        // stage B-tile
        const float* bg = Bbase + (size_t)(kt + brow) * 256 + bcol;
        *(float4*)&Bs[brow][bcol] = *(const float4*)bg;
        *(float4*)&Bs[brow][bcol + 4] = *(const float4*)(bg + 4);
        __syncthreads();
#pragma unroll
        for (int kk = 0; kk < 16; ++kk) {
            float4 a0 = *(const float4*)&Ast[kk][r0];
            float4 a1 = *(const float4*)&Ast[kk][r0 + 4];
            float4 b0 = *(const float4*)&Bs[kk][c0];
            float4 b1v = *(const float4*)&Bs[kk][c0 + 4];
            float ar[8] = {a0.x, a0.y, a0.z, a0.w, a1.x, a1.y, a1.z, a1.w};
            float br[8] = {b0.x, b0.y, b0.z, b0.w, b1v.x, b1v.y, b1v.z, b1v.w};
#pragma unroll
            for (int i2 = 0; i2 < 8; ++i2)
#pragma unroll
                for (int j2 = 0; j2 < 8; ++j2) acc[i2][j2] += ar[i2] * br[j2];
        }
        __syncthreads();
    }
#pragma unroll
    for (int i2 = 0; i2 < 8; ++i2) {
        int gm = bm * 128 + r0 + i2;
        if (gm < M) {
            *(float4*)(C + (size_t)gm * 256 + bn * 128 + c0) =
                make_float4(acc[i2][0], acc[i2][1], acc[i2][2], acc[i2][3]);
            *(float4*)(C + (size_t)gm * 256 + bn * 128 + c0 + 4) =
                make_float4(acc[i2][4], acc[i2][5], acc[i2][6], acc[i2][7]);
        }
    }
}

// ---------------- plain fp32 GEMM (fallback path): C[M,256] = A[M,256] * W2 ----------------

__global__ __launch_bounds__(256) void gemm_kernel(const float* __restrict__ A,
                                                   const float* __restrict__ B,
                                                   float* __restrict__ C, int M) {
    __shared__ float Ast[8][132];
    __shared__ float Bs[8][128];
    int tid = threadIdx.x;
    int bm = blockIdx.x, bn = blockIdx.y;
    int ty = tid >> 4, tx = tid & 15;
    int r0 = ty * 8, c0 = tx * 8;
    float acc[8][8] = {};
    int arow = tid >> 1, acol = (tid & 1) * 4;
    int brow = tid >> 5, bcol = (tid & 31) * 4;
    const float* Bbase = B + bn * 128;

    for (int kt = 0; kt < 256; kt += 8) {
        int gr = bm * 128 + arow;
        float4 av = (gr < M) ? *(const float4*)(A + (size_t)gr * 256 + kt + acol)
                             : make_float4(0.f, 0.f, 0.f, 0.f);
        Ast[acol + 0][arow] = av.x;
        Ast[acol + 1][arow] = av.y;
        Ast[acol + 2][arow] = av.z;
        Ast[acol + 3][arow] = av.w;
        *(float4*)&Bs[brow][bcol] = *(const float4*)(Bbase + (size_t)(kt + brow) * 256 + bcol);
        __syncthreads();
#pragma unroll
        for (int kk = 0; kk < 8; ++kk) {
            float4 a0 = *(const float4*)&Ast[kk][r0];
            float4 a1 = *(const float4*)&Ast[kk][r0 + 4];
            float4 b0 = *(const float4*)&Bs[kk][c0];
            float4 b1 = *(const float4*)&Bs[kk][c0 + 4];
            float ar[8] = {a0.x, a0.y, a0.z, a0.w, a1.x, a1.y, a1.z, a1.w};
            float br[8] = {b0.x, b0.y, b0.z, b0.w, b1.x, b1.y, b1.z, b1.w};
#pragma unroll
            for (int i2 = 0; i2 < 8; ++i2)
#pragma unroll
                for (int j2 = 0; j2 < 8; ++j2) acc[i2][j2] += ar[i2] * br[j2];
        }
        __syncthreads();
    }
#pragma unroll
    for (int i2 = 0; i2 < 8; ++i2) {
        int gm = bm * 128 + r0 + i2;
        if (gm < M) {
            *(float4*)(C + (size_t)gm * 256 + bn * 128 + c0) =
                make_float4(acc[i2][0], acc[i2][1], acc[i2][2], acc[i2][3]);
            *(float4*)(C + (size_t)gm * 256 + bn * 128 + c0 + 4) =
                make_float4(acc[i2][4], acc[i2][5], acc[i2][6], acc[i2][7]);
        }
    }
}

// ---------------- merge f64 pool partials -> f32 emb; zero LSTM flags ----------------

__global__ void merge_kernel(const double* __restrict__ embp, float* __restrict__ emb,
                             int* __restrict__ flags) {
    int k = blockIdx.x, c = threadIdx.x;
    double s = 0.0;
#pragma unroll
    for (int p = 0; p < 32; ++p) s += embp[((size_t)k * 32 + p) * 256 + c];
    emb[k * 256 + c] = (float)s;
    if (blockIdx.x == 0 && threadIdx.x < 2 * (KSTEPS + 1)) flags[threadIdx.x] = 0;
}

// ---------------- bidirectional LSTM: fused, 16 blocks/dir, cheap release/acquire sync ----

__global__ __launch_bounds__(256) void lstm_rec_kernel(
    const float* __restrict__ emb, float invN,
    const float* __restrict__ Wih_f, const float* __restrict__ Whh_f,
    const float* __restrict__ bih_f, const float* __restrict__ bhh_f,
    const float* __restrict__ Wih_b, const float* __restrict__ Whh_b,
    const float* __restrict__ bih_b, const float* __restrict__ bhh_b,
    float* __restrict__ hbuf, int* __restrict__ flags, float* __restrict__ out) {
    int dir = blockIdx.x >> 4;
    int seg = blockIdx.x & 15;
    const float* Wih = dir ? Wih_b : Wih_f;
    const float* Whh = dir ? Whh_b : Whh_f;
    const float* bih = dir ? bih_b : bih_f;
    const float* bhh = dir ? bhh_b : bhh_f;

    __shared__ float wh[64 * 256];
    __shared__ float wi[64 * 256];
    __shared__ float xs_s[KSTEPS * 256];
    __shared__ float gx[KSTEPS][64];
    __shared__ float garr[64];
    __shared__ float hprev_s[256];
    int tid = threadIdx.x;

    for (int v = tid; v < 64 * 64; v += 256) {
        int lrow = v >> 6;
        int c4 = (v & 63) * 4;
        int grow = ((lrow >> 4) << 8) + seg * 16 + (lrow & 15);
        *(float4*)&wh[lrow * 256 + c4] = *(const float4*)(Whh + (size_t)grow * 256 + c4);
        *(float4*)&wi[lrow * 256 + c4] = *(const float4*)(Wih + (size_t)grow * 256 + c4);
    }
    for (int idx = tid; idx < KSTEPS * 256; idx += 256) xs_s[idx] = emb[idx] * invN;
    __syncthreads();

    for (int d = tid; d < KSTEPS * 64; d += 256) {
        int st = d >> 6, lr = d & 63;
        const float* wr = &wi[lr << 8];
        const float* xr = &xs_s[st << 8];
        int r = (tid & 63) << 2;
        float acc = 0.f;
#pragma unroll 8
        for (int kk = 0; kk < 256; kk += 4) {
            int k2 = (kk + r) & 255;
            acc += wr[k2] * xr[k2] + wr[k2 + 1] * xr[k2 + 1] +
                   wr[k2 + 2] * xr[k2 + 2] + wr[k2 + 3] * xr[k2 + 3];
        }
        int grow = ((lr >> 4) << 8) + seg * 16 + (lr & 15);
        gx[st][lr] = acc + bih[grow] + bhh[grow];
    }

    int* flag = flags + dir * (KSTEPS + 1);
    float* hb = hbuf + dir * (KSTEPS + 1) * 256;

    if (tid < 16)
        __hip_atomic_store(&hb[seg * 16 + tid], 0.f, __ATOMIC_RELAXED, __HIP_MEMORY_SCOPE_AGENT);
    __syncthreads();
    if (tid == 0)
        __hip_atomic_fetch_add(&flag[0], 1, __ATOMIC_RELEASE, __HIP_MEMORY_SCOPE_AGENT);

    float c_reg = 0.f;

    for (int step = 0; step < KSTEPS; ++step) {
        if (tid == 0) {
            while (__hip_atomic_load(&flag[step], __ATOMIC_RELAXED, __HIP_MEMORY_SCOPE_AGENT) < 16) {
                __builtin_amdgcn_s_sleep(1);
            }
            (void)__hip_atomic_load(&flag[step], __ATOMIC_ACQUIRE, __HIP_MEMORY_SCOPE_AGENT);
        }
        __syncthreads();
        hprev_s[tid] = __hip_atomic_load(&hb[step * 256 + tid], __ATOMIC_RELAXED,
                                         __HIP_MEMORY_SCOPE_AGENT);
        __syncthreads();

        int d = tid >> 2, p = tid & 3;
        const float* wr = &wh[(d << 8) + (p << 6)];
        const float* hr = &hprev_s[p << 6];
        int rot = tid & 63;
        float acc = 0.f;
#pragma unroll 8
        for (int k = 0; k < 64; ++k) {
            int k2 = (k + rot) & 63;
            acc += wr[k2] * hr[k2];
        }
        acc += __shfl_xor(acc, 1);
        acc += __shfl_xor(acc, 2);
        if (p == 0) garr[d] = acc;
        __syncthreads();

        if (tid < 16) {
            float ig = sigmoidf(garr[tid] + gx[step][tid]);
            float fg = sigmoidf(garr[16 + tid] + gx[step][16 + tid]);
            float gg = tanhf(garr[32 + tid] + gx[step][32 + tid]);
            float og = sigmoidf(garr[48 + tid] + gx[step][48 + tid]);
            float cn = fg * c_reg + ig * gg;
            c_reg = cn;
            float hn = og * tanhf(cn);
            __hip_atomic_store(&hb[(step + 1) * 256 + seg * 16 + tid], hn, __ATOMIC_RELAXED,
                               __HIP_MEMORY_SCOPE_AGENT);
        }
        __syncthreads();
        if (tid == 0)
            __hip_atomic_fetch_add(&flag[step + 1], 1, __ATOMIC_RELEASE, __HIP_MEMORY_SCOPE_AGENT);
    }

    if (tid < 16)
        out[dir * 256 + seg * 16 + tid] =
            __hip_atomic_load(&hb[KSTEPS * 256 + seg * 16 + tid], __ATOMIC_RELAXED,
                              __HIP_MEMORY_SCOPE_AGENT);
}

// ---------------- launch ----------------

extern "C" void kernel_launch(void* const* d_in, const int* in_sizes, int n_in,
                              void* d_out, int out_size, void* d_ws, size_t ws_size,
                              hipStream_t stream) {
    const float* xs = (const float*)d_in[0];
    const int* edge_index = (const int*)d_in[1];
    const float* W1 = (const float*)d_in[2];
    const float* a_src1 = (const float*)d_in[3];
    const float* a_dst1 = (const float*)d_in[4];
    const float* b1 = (const float*)d_in[5];
    const float* W2 = (const float*)d_in[6];
    const float* a_src2 = (const float*)d_in[7];
    const float* a_dst2 = (const float*)d_in[8];
    const float* b2 = (const float*)d_in[9];
    const float* Wih_f = (const float*)d_in[10];
    const float* Whh_f = (const float*)d_in[11];
    const float* bih_f = (const float*)d_in[12];
    const float* bhh_f = (const float*)d_in[13];
    const float* Wih_b = (const float*)d_in[14];
    const float* Whh_b = (const float*)d_in[15];
    const float* bih_b = (const float*)d_in[16];
    const float* bhh_b = (const float*)d_in[17];

    const int K = KSTEPS;
    int D1 = in_sizes[2] / D2;
    int N = in_sizes[0] / (K * D1);
    int E = in_sizes[1] / (2 * K);
    int E2 = E + N;

    auto al = [](size_t x) { return (x + 255) & ~(size_t)255; };
    size_t fixed_sz = al((size_t)K * N * 4)
                    + al((size_t)K * (N + 1) * 4)
                    + al((size_t)K * N * 4)
                    + al((size_t)K * E2 * 4)
                    + al((size_t)K * 32 * 256 * 8)
                    + al((size_t)K * 256 * 4)
                    + al((size_t)2 * (K + 1) * 256 * 4)
                    + al((size_t)2 * (K + 1) * 4)
                    + al(16 * 4);
    int BK = 8;
    while (BK > 1) {
        size_t need = fixed_sz + 3 * al((size_t)BK * N * 8 * 4) + 2 * al((size_t)BK * N * 256 * 4);
        if (need <= ws_size) break;
        BK >>= 1;
    }

    char* w = (char*)d_ws;
    auto alloc = [&](size_t bytes) { char* p = w; w += (bytes + 255) & ~(size_t)255; return p; };
    int* counts = (int*)alloc((size_t)K * N * 4);
    int* row_ptr = (int*)alloc((size_t)K * (N + 1) * 4);
    int* fill = (int*)alloc((size_t)K * N * 4);
    int* ein = (int*)alloc((size_t)K * E2 * 4);
    double* embp = (double*)alloc((size_t)K * 32 * 256 * 8);
    float* emb = (float*)alloc((size_t)K * 256 * 4);
    float* hbuf = (float*)alloc((size_t)2 * (K + 1) * 256 * 4);
    int* flags = (int*)alloc((size_t)2 * (K + 1) * 4);
    float* Pvec = (float*)alloc(16 * 4);
    float* Sbuf = (float*)alloc((size_t)BK * N * 8 * 4);
    float* s_src = (float*)alloc((size_t)BK * N * 8 * 4);
    float* s_dst = (float*)alloc((size_t)BK * N * 8 * 4);
    float* bufA = (float*)alloc((size_t)BK * N * 256 * 4);
    float* bufB = (float*)alloc((size_t)BK * N * 256 * 4);

    int KN = K * N;
    int NEMBP = K * 32 * 256;
    int zblk = ((KN > NEMBP ? KN : NEMBP) + 255) / 256;
    zero_all_kernel<<<zblk, 256, 0, stream>>>(counts, fill, embp, KN, NEMBP,
                                              W1, a_src1, a_dst1, Pvec, D1);
    int eblk = (E2 + 255) / 256;
    count_all_kernel<<<eblk * K, 256, 0, stream>>>(edge_index, E, N, K, counts);
    scan_all_kernel<<<K, 1024, 0, stream>>>(counts, row_ptr, N);
    scatter_all_kernel<<<eblk * K, 256, 0, stream>>>(edge_index, E, N, K, row_ptr, fill, ein);

    int nblk4 = (N + 3) / 4;
    int sblk = (N * 8 + 255) / 256;
    for (int k0 = 0; k0 < K; k0 += BK) {
        int BKcur = (K - k0 < BK) ? (K - k0) : BK;
        if (D1 == 1) {
            agg1s_all_kernel<<<nblk4 * BKcur, 256, 0, stream>>>(
                xs, Pvec, row_ptr, ein, Sbuf, N, E2, k0, BKcur);
            int M = BKcur * N;
            gemm_fused_kernel<<<dim3((M + 127) / 128, 2), 256, 0, stream>>>(
                Sbuf, W1, b1, W2, bufA, M);
            s_all_kernel<<<dim3(sblk, BKcur), 256, 0, stream>>>(bufA, a_src2, a_dst2,
                                                                s_src, s_dst, N);
            agg2pool_kernel<<<nblk4 * BKcur, 256, 0, stream>>>(
                bufA, s_src, s_dst, row_ptr, ein, b2, embp, N, E2, k0, BKcur);
        } else {
            for (int kk = 0; kk < BKcur; ++kk) {
                int k = k0 + kk;
                const float* xk = xs + (size_t)k * N * D1;
                h1_kernel<<<(N * 256 + 255) / 256, 256, 0, stream>>>(xk, W1, bufA, N, D1);
                s_all_kernel<<<dim3(sblk, 1), 256, 0, stream>>>(bufA, a_src1, a_dst1,
                                                                s_src, s_dst, N);
                agg2_out_kernel<<<nblk4, 256, 0, stream>>>(bufA, s_src, s_dst, row_ptr, ein,
                                                           b1, bufB, N, E2, k);
                gemm_kernel<<<dim3((N + 127) / 128, 2), 256, 0, stream>>>(bufB, W2, bufA, N);
                s_all_kernel<<<dim3(sblk, 1), 256, 0, stream>>>(bufA, a_src2, a_dst2,
                                                                s_src, s_dst, N);
                agg2pool_kernel<<<nblk4, 256, 0, stream>>>(
                    bufA, s_src, s_dst, row_ptr, ein, b2, embp, N, E2, k, 1);
            }
        }
    }

    merge_kernel<<<K, 256, 0, stream>>>(embp, emb, flags);
    lstm_rec_kernel<<<32, 256, 0, stream>>>(emb, 1.f / (float)N,
                                            Wih_f, Whh_f, bih_f, bhh_f,
                                            Wih_b, Whh_b, bih_b, bhh_b,
                                            hbuf, flags, (float*)d_out);
}